// Round 1
// baseline (1852.428 us; speedup 1.0000x reference)
//
#include <hip/hip_runtime.h>
#include <hip/hip_bf16.h>
#include <math.h>

typedef unsigned int u32;
typedef unsigned short u16;
typedef __bf16 bf16t;
typedef bf16t bf16x8 __attribute__((ext_vector_type(8)));
typedef float f32x4 __attribute__((ext_vector_type(4)));

__device__ __forceinline__ u16 f2bf(float f) {
    u32 u = __builtin_bit_cast(u32, f);
    u32 r = (u + 0x7fffu + ((u >> 16) & 1u)) >> 16;
    return (u16)r;
}

// ---------------- weight layout transforms (fp32 -> fp32, (o, k*512+i)) ----------------
__global__ void tdeconv_k(const float* __restrict__ src, float* __restrict__ dst) {
    int o = blockIdx.x;
    for (int i = threadIdx.x; i < 512; i += blockDim.x) {
        const float* s = src + ((size_t)i * 512 + o) * 5;   // deconv_w (in, out, K)
        #pragma unroll
        for (int k = 0; k < 5; ++k)
            dst[(size_t)o * 2560 + k * 512 + i] = s[k];
    }
}
__global__ void tconv_k(const float* __restrict__ src, float* __restrict__ dst) {
    int o = blockIdx.x, st = blockIdx.y;
    const float* bsrc = src + (size_t)st * 512 * 512 * 5;   // conv_w (2, out, in, K)
    float* bdst = dst + (size_t)st * 512 * 2560;
    for (int i = threadIdx.x; i < 512; i += blockDim.x) {
        const float* s = bsrc + ((size_t)o * 512 + i) * 5;
        #pragma unroll
        for (int k = 0; k < 5; ++k)
            bdst[(size_t)o * 2560 + k * 512 + i] = s[k];
    }
}
__global__ void tsmooth_k(const float* __restrict__ src, float* __restrict__ dst) {
    int o = blockIdx.x;                                      // smooth_w (OUT, in, K)
    for (int i = threadIdx.x; i < 512; i += blockDim.x) {
        const float* s = src + ((size_t)o * 512 + i) * 5;
        #pragma unroll
        for (int k = 0; k < 5; ++k)
            dst[(size_t)o * 2560 + k * 512 + i] = s[k];
    }
}
__global__ void cvt_bf_k(const float* __restrict__ in, u16* __restrict__ out, int n4) {
    int i = blockIdx.x * blockDim.x + threadIdx.x;
    if (i < n4) {
        float4 v = ((const float4*)in)[i];
        u32 lo = (u32)f2bf(v.x) | ((u32)f2bf(v.y) << 16);
        u32 hi = (u32)f2bf(v.z) | ((u32)f2bf(v.w) << 16);
        ((uint2*)out)[i] = make_uint2(lo, hi);
    }
}

// ---------------- universal GEMM: C[M,N] = gatherA[M,K](bf16) @ W[N,K](f32->bf16) ----------------
enum { M_IDENT = 0, M_DECONV, M_CONV1, M_CONV2, M_EMBED, M_SMOOTH };
enum { E_BIAS = 1, E_LEAKY = 2, E_BN = 4, E_GELU = 8, E_RES = 16, E_OUTF = 32, E_OUTB = 64 };

template<int MODE, int EPI>
__global__ __launch_bounds__(256) void gemm_k(
    const u16* __restrict__ A, const float* __restrict__ W,
    const float* __restrict__ bias,
    const float* __restrict__ bng, const float* __restrict__ bnbt,
    const float* __restrict__ bnm, const float* __restrict__ bnv,
    const float* __restrict__ resid,
    float* __restrict__ outF, u16* __restrict__ outB,
    const u16* __restrict__ zrow, int N, int K)
{
    __shared__ u16 As[128 * 32];
    __shared__ u16 Bs[128 * 32];
    const int tid = threadIdx.x;
    const int lane = tid & 63, w = tid >> 6;
    const int l15 = lane & 15, hi4 = lane >> 4;
    const int bn = blockIdx.x, bm = blockIdx.y;
    const int wm = (w >> 1) * 64, wn = (w & 1) * 64;
    const f32x4 fz = {0.f, 0.f, 0.f, 0.f};
    f32x4 acc[4][4];
    #pragma unroll
    for (int i = 0; i < 4; ++i)
        #pragma unroll
        for (int j = 0; j < 4; ++j) acc[i][j] = fz;

    for (int k0 = 0; k0 < K; k0 += 32) {
        __syncthreads();
        // ---- stage A tile (128 x 32 bf16), with conv gather ----
        const int tap = k0 >> 9;
        #pragma unroll
        for (int p = 0; p < 2; ++p) {
            int idx = p * 256 + tid;
            int r = idx >> 2, c4 = idx & 3;
            int grow = bm * 128 + r;
            int koff = (k0 & 511) + c4 * 8;
            const u16* src;
            if constexpr (MODE == M_IDENT) {
                src = A + (size_t)grow * K + k0 + c4 * 8;
            } else if constexpr (MODE == M_DECONV) {
                int b = grow >> 7, t = grow & 127;
                int num = t + 2 - tap;
                bool ok = (num >= 0) && ((num & 1) == 0) && ((num >> 1) < 64);
                src = ok ? (A + ((size_t)(b * 64 + (num >> 1))) * 512 + koff) : (zrow + koff);
            } else if constexpr (MODE == M_CONV1) {
                int b = grow >> 7, t = grow & 127;
                int s = t + tap - 2; s = s < 0 ? 0 : (s > 127 ? 127 : s);
                src = A + ((size_t)(b * 128 + s)) * 512 + koff;
            } else if constexpr (MODE == M_CONV2) {
                int b = grow >> 8, t = grow & 255;
                int s = t + tap - 2; s = s < 0 ? 0 : (s > 255 ? 255 : s);
                src = A + ((size_t)(b * 128 + (s >> 1))) * 512 + koff;
            } else if constexpr (MODE == M_EMBED) {
                int b = grow >> 9, t = grow & 511;
                src = A + ((size_t)(b * 256 + (t >> 1))) * 512 + koff;
            } else { // M_SMOOTH
                int b = grow >> 9, t = grow & 511;
                int s = t + tap - 2;
                bool ok = (s >= 0) && (s < 512);
                src = ok ? (A + ((size_t)(b * 512 + s)) * 512 + koff) : (zrow + koff);
            }
            uint4 v = *(const uint4*)src;
            *(uint4*)&As[r * 32 + c4 * 8] = v;
        }
        // ---- stage B tile (128 x 32), fp32 -> bf16 ----
        #pragma unroll
        for (int p = 0; p < 4; ++p) {
            int idx = p * 256 + tid;
            int r = idx >> 3, c = idx & 7;
            float4 v = *(const float4*)(W + (size_t)(bn * 128 + r) * K + k0 + c * 4);
            u32 lo = (u32)f2bf(v.x) | ((u32)f2bf(v.y) << 16);
            u32 hi = (u32)f2bf(v.z) | ((u32)f2bf(v.w) << 16);
            *(uint2*)&Bs[r * 32 + c * 4] = make_uint2(lo, hi);
        }
        __syncthreads();
        // ---- compute ----
        bf16x8 af[4], bf[4];
        #pragma unroll
        for (int i = 0; i < 4; ++i)
            af[i] = *(const bf16x8*)&As[(wm + i * 16 + l15) * 32 + hi4 * 8];
        #pragma unroll
        for (int i = 0; i < 4; ++i)
            bf[i] = *(const bf16x8*)&Bs[(wn + i * 16 + l15) * 32 + hi4 * 8];
        #pragma unroll
        for (int mi = 0; mi < 4; ++mi)
            #pragma unroll
            for (int ni = 0; ni < 4; ++ni)
                acc[mi][ni] = __builtin_amdgcn_mfma_f32_16x16x32_bf16(af[mi], bf[ni], acc[mi][ni], 0, 0, 0);
    }
    // ---- epilogue ----
    #pragma unroll
    for (int mi = 0; mi < 4; ++mi) {
        #pragma unroll
        for (int ni = 0; ni < 4; ++ni) {
            int col = bn * 128 + wn + ni * 16 + l15;
            #pragma unroll
            for (int r = 0; r < 4; ++r) {
                int row = bm * 128 + wm + mi * 16 + hi4 * 4 + r;
                float v = acc[mi][ni][r];
                if constexpr (EPI & E_BIAS) v += bias[col];
                if constexpr (EPI & E_LEAKY) v = v >= 0.f ? v : 0.2f * v;
                if constexpr (EPI & E_BN)
                    v = (v - bnm[col]) * (bng[col] * rsqrtf(bnv[col] + 1e-5f)) + bnbt[col];
                if constexpr (EPI & E_GELU) v = 0.5f * v * (1.f + erff(v * 0.70710678118654752f));
                if constexpr (EPI & E_RES) v += resid[(size_t)row * N + col];
                if constexpr (EPI & E_OUTF) outF[(size_t)row * N + col] = v;
                if constexpr (EPI & E_OUTB) outB[(size_t)row * N + col] = f2bf(v);
            }
        }
    }
}

// ---------------- flash attention: block = (qchunk 64, head, batch), 4 waves x 16 q-rows ----------------
__global__ __launch_bounds__(256) void attn_k(const u16* __restrict__ qkv, u16* __restrict__ outp)
{
    __shared__ u16 Ks[64 * 64];
    __shared__ u16 Vt[64 * 64];
    __shared__ u16 Ps[4][16 * 64];
    const int tid = threadIdx.x;
    const int lane = tid & 63, w = tid >> 6;
    const int l15 = lane & 15, hi4 = lane >> 4;
    const int qc = blockIdx.x, h = blockIdx.y, b = blockIdx.z;
    const int qrow = qc * 64 + w * 16 + l15;
    const size_t tq = ((size_t)b * 512 + qrow) * 1536 + h * 64;
    bf16x8 qf0 = *(const bf16x8*)&qkv[tq + hi4 * 8];
    bf16x8 qf1 = *(const bf16x8*)&qkv[tq + 32 + hi4 * 8];
    const float slope = exp2f(-(float)(h + 1));
    const f32x4 fz = {0.f, 0.f, 0.f, 0.f};
    float m_run = -3.0e38f, l_run = 0.f;
    f32x4 oacc[4] = {fz, fz, fz, fz};

    for (int j = 0; j < 8; ++j) {
        __syncthreads();
        #pragma unroll
        for (int p = 0; p < 2; ++p) {
            int idx = p * 256 + tid;
            int r = idx >> 3, c = idx & 7;
            size_t tk = ((size_t)b * 512 + j * 64 + r) * 1536 + h * 64;
            uint4 kvec = *(const uint4*)&qkv[tk + 512 + c * 8];
            *(uint4*)&Ks[r * 64 + c * 8] = kvec;
            uint4 vvec = *(const uint4*)&qkv[tk + 1024 + c * 8];
            u32 vv_[4] = {vvec.x, vvec.y, vvec.z, vvec.w};
            #pragma unroll
            for (int q2 = 0; q2 < 4; ++q2) {
                Vt[(c * 8 + q2 * 2) * 64 + r] = (u16)(vv_[q2] & 0xffffu);
                Vt[(c * 8 + q2 * 2 + 1) * 64 + r] = (u16)(vv_[q2] >> 16);
            }
        }
        __syncthreads();
        // scores: S^T tiles via mfma(K, Q): lane holds q=l15, k = j*64 + g*16 + hi4*4 + r
        float s[16];
        #pragma unroll
        for (int g = 0; g < 4; ++g) {
            f32x4 st = fz;
            bf16x8 kf0 = *(const bf16x8*)&Ks[(g * 16 + l15) * 64 + hi4 * 8];
            st = __builtin_amdgcn_mfma_f32_16x16x32_bf16(kf0, qf0, st, 0, 0, 0);
            bf16x8 kf1 = *(const bf16x8*)&Ks[(g * 16 + l15) * 64 + 32 + hi4 * 8];
            st = __builtin_amdgcn_mfma_f32_16x16x32_bf16(kf1, qf1, st, 0, 0, 0);
            #pragma unroll
            for (int r = 0; r < 4; ++r) {
                int kabs = j * 64 + g * 16 + hi4 * 4 + r;
                s[g * 4 + r] = st[r] * 0.125f - slope * fabsf((float)(qrow - kabs));
            }
        }
        // online softmax (row = q = l15, replicated over hi4 groups)
        float pm = s[0];
        #pragma unroll
        for (int i = 1; i < 16; ++i) pm = fmaxf(pm, s[i]);
        pm = fmaxf(pm, __shfl_xor(pm, 16));
        pm = fmaxf(pm, __shfl_xor(pm, 32));
        float m_new = fmaxf(m_run, pm);
        float alpha = expf(m_run - m_new);
        float p[16], ps = 0.f;
        #pragma unroll
        for (int i = 0; i < 16; ++i) { p[i] = expf(s[i] - m_new); ps += p[i]; }
        ps += __shfl_xor(ps, 16);
        ps += __shfl_xor(ps, 32);
        l_run = l_run * alpha + ps;
        m_run = m_new;
        #pragma unroll
        for (int n = 0; n < 4; ++n) oacc[n] *= alpha;
        // P -> LDS (wave-private region), row q, contiguous k
        #pragma unroll
        for (int g = 0; g < 4; ++g)
            #pragma unroll
            for (int rp = 0; rp < 2; ++rp) {
                u32 pk = (u32)f2bf(p[g * 4 + rp * 2]) | ((u32)f2bf(p[g * 4 + rp * 2 + 1]) << 16);
                *(u32*)&Ps[w][l15 * 64 + g * 16 + hi4 * 4 + rp * 2] = pk;
            }
        // O^T += V^T @ P^T : mfma(A=Vt rows (d), B=P rows (q))
        #pragma unroll
        for (int n = 0; n < 4; ++n) {
            #pragma unroll
            for (int kk = 0; kk < 2; ++kk) {
                bf16x8 vf = *(const bf16x8*)&Vt[(n * 16 + l15) * 64 + kk * 32 + hi4 * 8];
                bf16x8 pf = *(const bf16x8*)&Ps[w][l15 * 64 + kk * 32 + hi4 * 8];
                oacc[n] = __builtin_amdgcn_mfma_f32_16x16x32_bf16(vf, pf, oacc[n], 0, 0, 0);
            }
        }
    }
    const float inv = 1.f / l_run;
    const size_t to = ((size_t)b * 512 + qrow) * 512 + h * 64;
    #pragma unroll
    for (int n = 0; n < 4; ++n) {
        u32 lo = (u32)f2bf(oacc[n][0] * inv) | ((u32)f2bf(oacc[n][1] * inv) << 16);
        u32 hi = (u32)f2bf(oacc[n][2] * inv) | ((u32)f2bf(oacc[n][3] * inv) << 16);
        *(uint2*)&outp[to + n * 16 + hi4 * 4] = make_uint2(lo, hi);
    }
}

// ---------------- LayerNorm: wave per row, writes f32 residual + bf16 ----------------
__global__ __launch_bounds__(256) void ln_k(const float* __restrict__ in,
    const float* __restrict__ g, const float* __restrict__ bt,
    float* __restrict__ outF, u16* __restrict__ outB)
{
    const int lane = threadIdx.x & 63, w = threadIdx.x >> 6;
    const size_t row = (size_t)blockIdx.x * 4 + w;
    const float* rp = in + row * 512;
    const int c0 = lane * 8;
    float4 a = *(const float4*)&rp[c0];
    float4 bv = *(const float4*)&rp[c0 + 4];
    float v[8] = {a.x, a.y, a.z, a.w, bv.x, bv.y, bv.z, bv.w};
    float s = 0.f, q = 0.f;
    #pragma unroll
    for (int i = 0; i < 8; ++i) { s += v[i]; q += v[i] * v[i]; }
    #pragma unroll
    for (int d = 1; d < 64; d <<= 1) { s += __shfl_xor(s, d); q += __shfl_xor(q, d); }
    float mean = s * (1.f / 512.f);
    float var = q * (1.f / 512.f) - mean * mean;
    float rstd = rsqrtf(var + 1e-5f);
    float y[8];
    #pragma unroll
    for (int i = 0; i < 8; ++i) y[i] = (v[i] - mean) * rstd * g[c0 + i] + bt[c0 + i];
    *(float4*)&outF[row * 512 + c0] = make_float4(y[0], y[1], y[2], y[3]);
    *(float4*)&outF[row * 512 + c0 + 4] = make_float4(y[4], y[5], y[6], y[7]);
    u32 pk[4];
    #pragma unroll
    for (int i = 0; i < 4; ++i)
        pk[i] = (u32)f2bf(y[i * 2]) | ((u32)f2bf(y[i * 2 + 1]) << 16);
    *(uint4*)&outB[row * 512 + c0] = make_uint4(pk[0], pk[1], pk[2], pk[3]);
}

extern "C" void kernel_launch(void* const* d_in, const int* in_sizes, int n_in,
                              void* d_out, int out_size, void* d_ws, size_t ws_size,
                              hipStream_t stream)
{
    (void)in_sizes; (void)n_in; (void)out_size; (void)ws_size;
    const float* inputs   = (const float*)d_in[0];
    const float* deconv_w = (const float*)d_in[1];
    const float* deconv_b = (const float*)d_in[2];
    const float* bn_gamma = (const float*)d_in[3];
    const float* bn_beta  = (const float*)d_in[4];
    const float* bn_mean  = (const float*)d_in[5];
    const float* bn_var   = (const float*)d_in[6];
    const float* conv_w   = (const float*)d_in[7];
    const float* conv_b   = (const float*)d_in[8];
    const float* emb_w    = (const float*)d_in[9];
    const float* emb_b    = (const float*)d_in[10];
    const float* qkv_w    = (const float*)d_in[11];
    const float* qkv_b    = (const float*)d_in[12];
    const float* outp_w   = (const float*)d_in[13];
    const float* outp_b   = (const float*)d_in[14];
    const float* ln1_g    = (const float*)d_in[15];
    const float* ln1_b    = (const float*)d_in[16];
    const float* ff1_w    = (const float*)d_in[17];
    const float* ff1_b    = (const float*)d_in[18];
    const float* ff2_w    = (const float*)d_in[19];
    const float* ff2_b    = (const float*)d_in[20];
    const float* ln2_g    = (const float*)d_in[21];
    const float* ln2_b    = (const float*)d_in[22];
    const float* smooth_w = (const float*)d_in[23];
    const float* smooth_b = (const float*)d_in[24];
    float* out = (float*)d_out;

    char* ws = (char*)d_ws;
    size_t off = 0;
    auto alloc = [&](size_t bytes) -> void* {
        void* p = ws + off;
        off += (bytes + 255) & ~(size_t)255;
        return p;
    };
    u16*   zrow    = (u16*)alloc(1024);
    u16*   in_bf   = (u16*)alloc((size_t)16 * 64 * 512 * 2);
    float* Wd      = (float*)alloc((size_t)512 * 2560 * 4);
    float* Wc      = (float*)alloc((size_t)2 * 512 * 2560 * 4);
    float* Wsm     = (float*)alloc((size_t)128 * 2560 * 4);
    u16*   e0      = (u16*)alloc((size_t)2048 * 512 * 2);
    u16*   e1      = (u16*)alloc((size_t)2048 * 512 * 2);
    u16*   e2      = (u16*)alloc((size_t)4096 * 512 * 2);
    float* x_f     = (float*)alloc((size_t)8192 * 512 * 4);
    u16*   x_bf    = (u16*)alloc((size_t)8192 * 512 * 2);
    u16*   qkv_bf  = (u16*)alloc((size_t)8192 * 1536 * 2);
    u16*   attn_bf = (u16*)alloc((size_t)8192 * 512 * 2);
    float* tmp_f   = (float*)alloc((size_t)8192 * 512 * 4);
    u16*   h_bf    = (u16*)alloc((size_t)8192 * 2048 * 2);

    hipMemsetAsync(zrow, 0, 1024, stream);
    cvt_bf_k<<<dim3(512), dim3(256), 0, stream>>>(inputs, in_bf, 131072);
    tdeconv_k<<<dim3(512), dim3(256), 0, stream>>>(deconv_w, Wd);
    tconv_k<<<dim3(512, 2), dim3(256), 0, stream>>>(conv_w, Wc);
    tsmooth_k<<<dim3(128), dim3(256), 0, stream>>>(smooth_w, Wsm);

    // ---- expander ----
    gemm_k<M_DECONV, E_BIAS | E_LEAKY | E_BN | E_OUTB><<<dim3(4, 16), 256, 0, stream>>>(
        in_bf, Wd, deconv_b, bn_gamma, bn_beta, bn_mean, bn_var,
        nullptr, nullptr, e0, zrow, 512, 2560);
    gemm_k<M_CONV1, E_BIAS | E_LEAKY | E_BN | E_OUTB><<<dim3(4, 16), 256, 0, stream>>>(
        e0, Wc, conv_b, bn_gamma + 512, bn_beta + 512, bn_mean + 512, bn_var + 512,
        nullptr, nullptr, e1, zrow, 512, 2560);
    gemm_k<M_CONV2, E_BIAS | E_LEAKY | E_BN | E_OUTB><<<dim3(4, 32), 256, 0, stream>>>(
        e1, Wc + (size_t)512 * 2560, conv_b + 512, bn_gamma + 1024, bn_beta + 1024,
        bn_mean + 1024, bn_var + 1024, nullptr, nullptr, e2, zrow, 512, 2560);
    gemm_k<M_EMBED, E_BIAS | E_OUTF | E_OUTB><<<dim3(4, 64), 256, 0, stream>>>(
        e2, emb_w, emb_b, nullptr, nullptr, nullptr, nullptr,
        nullptr, x_f, x_bf, zrow, 512, 512);

    // ---- transformer ----
    for (int l = 0; l < 6; ++l) {
        gemm_k<M_IDENT, E_BIAS | E_OUTB><<<dim3(12, 64), 256, 0, stream>>>(
            x_bf, qkv_w + (size_t)l * 1536 * 512, qkv_b + l * 1536,
            nullptr, nullptr, nullptr, nullptr, nullptr, nullptr, qkv_bf, zrow, 1536, 512);
        attn_k<<<dim3(8, 8, 16), 256, 0, stream>>>(qkv_bf, attn_bf);
        gemm_k<M_IDENT, E_BIAS | E_RES | E_OUTF><<<dim3(4, 64), 256, 0, stream>>>(
            attn_bf, outp_w + (size_t)l * 512 * 512, outp_b + l * 512,
            nullptr, nullptr, nullptr, nullptr, x_f, tmp_f, nullptr, zrow, 512, 512);
        ln_k<<<dim3(2048), 256, 0, stream>>>(tmp_f, ln1_g + l * 512, ln1_b + l * 512, x_f, x_bf);
        gemm_k<M_IDENT, E_BIAS | E_GELU | E_OUTB><<<dim3(16, 64), 256, 0, stream>>>(
            x_bf, ff1_w + (size_t)l * 2048 * 512, ff1_b + l * 2048,
            nullptr, nullptr, nullptr, nullptr, nullptr, nullptr, h_bf, zrow, 2048, 512);
        gemm_k<M_IDENT, E_BIAS | E_RES | E_OUTF><<<dim3(4, 64), 256, 0, stream>>>(
            h_bf, ff2_w + (size_t)l * 512 * 2048, ff2_b + l * 512,
            nullptr, nullptr, nullptr, nullptr, x_f, tmp_f, nullptr, zrow, 512, 2048);
        ln_k<<<dim3(2048), 256, 0, stream>>>(tmp_f, ln2_g + l * 512, ln2_b + l * 512, x_f, x_bf);
    }

    // ---- smooth conv -> output ----
    gemm_k<M_SMOOTH, E_BIAS | E_OUTF><<<dim3(1, 64), 256, 0, stream>>>(
        x_bf, Wsm, smooth_b, nullptr, nullptr, nullptr, nullptr,
        nullptr, out, nullptr, zrow, 128, 2560);
}

// Round 2
// 1375.219 us; speedup vs baseline: 1.3470x; 1.3470x over previous
//
#include <hip/hip_runtime.h>
#include <hip/hip_bf16.h>
#include <math.h>

typedef unsigned int u32;
typedef unsigned short u16;
typedef __bf16 bf16t;
typedef bf16t bf16x8 __attribute__((ext_vector_type(8)));
typedef float f32x4 __attribute__((ext_vector_type(4)));

__device__ __forceinline__ u16 f2bf(float f) {
    u32 u = __builtin_bit_cast(u32, f);
    u32 r = (u + 0x7fffu + ((u >> 16) & 1u)) >> 16;
    return (u16)r;
}

__device__ __forceinline__ void gl_lds16(const u16* g, u16* l) {
    __builtin_amdgcn_global_load_lds(
        (const __attribute__((address_space(1))) void*)g,
        (__attribute__((address_space(3))) void*)l, 16, 0, 0);
}

// ---------------- weight layout transforms (-> bf16, (o, k*512+i)) ----------------
__global__ void tdeconv_k(const float* __restrict__ src, u16* __restrict__ dst) {
    int o = blockIdx.x;
    for (int i = threadIdx.x; i < 512; i += blockDim.x) {
        const float* s = src + ((size_t)i * 512 + o) * 5;   // deconv_w (in, out, K)
        #pragma unroll
        for (int k = 0; k < 5; ++k)
            dst[(size_t)o * 2560 + k * 512 + i] = f2bf(s[k]);
    }
}
__global__ void tconv_k(const float* __restrict__ src, u16* __restrict__ dst) {
    int o = blockIdx.x, st = blockIdx.y;
    const float* bsrc = src + (size_t)st * 512 * 512 * 5;   // conv_w (2, out, in, K)
    u16* bdst = dst + (size_t)st * 512 * 2560;
    for (int i = threadIdx.x; i < 512; i += blockDim.x) {
        const float* s = bsrc + ((size_t)o * 512 + i) * 5;
        #pragma unroll
        for (int k = 0; k < 5; ++k)
            bdst[(size_t)o * 2560 + k * 512 + i] = f2bf(s[k]);
    }
}
__global__ void tsmooth_k(const float* __restrict__ src, u16* __restrict__ dst) {
    int o = blockIdx.x;                                      // smooth_w (OUT, in, K)
    for (int i = threadIdx.x; i < 512; i += blockDim.x) {
        const float* s = src + ((size_t)o * 512 + i) * 5;
        #pragma unroll
        for (int k = 0; k < 5; ++k)
            dst[(size_t)o * 2560 + k * 512 + i] = f2bf(s[k]);
    }
}
__global__ void cvt_bf_k(const float* __restrict__ in, u16* __restrict__ out, int n4) {
    int i = blockIdx.x * blockDim.x + threadIdx.x;
    if (i < n4) {
        float4 v = ((const float4*)in)[i];
        u32 lo = (u32)f2bf(v.x) | ((u32)f2bf(v.y) << 16);
        u32 hi = (u32)f2bf(v.z) | ((u32)f2bf(v.w) << 16);
        ((uint2*)out)[i] = make_uint2(lo, hi);
    }
}

// ---------------- universal GEMM: C[M,N] = gatherA[M,K](bf16) @ W[N,K](bf16) ----------------
enum { M_IDENT = 0, M_DECONV, M_CONV1, M_CONV2, M_EMBED, M_SMOOTH };
enum { E_BIAS = 1, E_LEAKY = 2, E_BN = 4, E_GELU = 8, E_RES = 16, E_OUTF = 32, E_OUTB = 64 };

template<int MODE, int EPI, int BM, int BN, int WM, int WN>
__global__ __launch_bounds__(256) void gemm_k(
    const u16* __restrict__ A, const u16* __restrict__ W,
    const float* __restrict__ bias,
    const float* __restrict__ bng, const float* __restrict__ bnbt,
    const float* __restrict__ bnm, const float* __restrict__ bnv,
    const float* __restrict__ resid,
    float* __restrict__ outF, u16* __restrict__ outB,
    const u16* __restrict__ zrow, int N, int K)
{
    constexpr int FM = BM / WM / 16, FN = BN / WN / 16;
    constexpr int APW = BM / 64, BPW = BN / 64;   // 1KB staging chunks per wave
    __shared__ u16 As[BM * 32];
    __shared__ u16 Bs[BN * 32];
    const int tid = threadIdx.x;
    const int lane = tid & 63, w = tid >> 6;
    const int l15 = lane & 15, hi4 = lane >> 4;
    const int bn = blockIdx.x, bm = blockIdx.y;
    const int wr = w / WN, wc = w % WN;
    const int rowb = wr * (BM / WM), colb = wc * (BN / WN);
    const int lr = lane >> 2, lc8 = (lane & 3) * 8;
    f32x4 acc[FM][FN] = {};

    for (int k0 = 0; k0 < K; k0 += 32) {
        __syncthreads();
        const int tap = k0 >> 9;
        const int koff = (k0 & 511) + lc8;
        #pragma unroll
        for (int p = 0; p < APW; ++p) {
            const int j = w * APW + p;
            const int r = j * 16 + lr;
            const int grow = bm * BM + r;
            const u16* src;
            if constexpr (MODE == M_IDENT) {
                src = A + (size_t)grow * K + k0 + lc8;
            } else if constexpr (MODE == M_DECONV) {
                int b = grow >> 7, t = grow & 127;
                int num = t + 2 - tap;
                bool ok = (num >= 0) && ((num & 1) == 0) && ((num >> 1) < 64);
                src = ok ? (A + ((size_t)(b * 64 + (num >> 1))) * 512 + koff) : (zrow + koff);
            } else if constexpr (MODE == M_CONV1) {
                int b = grow >> 7, t = grow & 127;
                int s = t + tap - 2; s = s < 0 ? 0 : (s > 127 ? 127 : s);
                src = A + ((size_t)(b * 128 + s)) * 512 + koff;
            } else if constexpr (MODE == M_CONV2) {
                int b = grow >> 8, t = grow & 255;
                int s = t + tap - 2; s = s < 0 ? 0 : (s > 255 ? 255 : s);
                src = A + ((size_t)(b * 128 + (s >> 1))) * 512 + koff;
            } else if constexpr (MODE == M_EMBED) {
                int b = grow >> 9, t = grow & 511;
                src = A + ((size_t)(b * 256 + (t >> 1))) * 512 + koff;
            } else { // M_SMOOTH
                int b = grow >> 9, t = grow & 511;
                int s = t + tap - 2;
                bool ok = (s >= 0) && (s < 512);
                src = ok ? (A + ((size_t)(b * 512 + s)) * 512 + koff) : (zrow + koff);
            }
            gl_lds16(src, &As[j * 512]);
        }
        #pragma unroll
        for (int p = 0; p < BPW; ++p) {
            const int j = w * BPW + p;
            const int r = j * 16 + lr;
            gl_lds16(W + (size_t)(bn * BN + r) * K + k0 + lc8, &Bs[j * 512]);
        }
        __syncthreads();
        bf16x8 af[FM], bfr[FN];
        #pragma unroll
        for (int mi = 0; mi < FM; ++mi)
            af[mi] = *(const bf16x8*)&As[(rowb + mi * 16 + l15) * 32 + hi4 * 8];
        #pragma unroll
        for (int ni = 0; ni < FN; ++ni)
            bfr[ni] = *(const bf16x8*)&Bs[(colb + ni * 16 + l15) * 32 + hi4 * 8];
        #pragma unroll
        for (int mi = 0; mi < FM; ++mi)
            #pragma unroll
            for (int ni = 0; ni < FN; ++ni)
                acc[mi][ni] = __builtin_amdgcn_mfma_f32_16x16x32_bf16(af[mi], bfr[ni], acc[mi][ni], 0, 0, 0);
    }
    // ---- epilogue ----
    #pragma unroll
    for (int mi = 0; mi < FM; ++mi) {
        #pragma unroll
        for (int ni = 0; ni < FN; ++ni) {
            const int col = bn * BN + colb + ni * 16 + l15;
            #pragma unroll
            for (int r = 0; r < 4; ++r) {
                const int row = bm * BM + rowb + mi * 16 + hi4 * 4 + r;
                float v = acc[mi][ni][r];
                if constexpr (EPI & E_BIAS) v += bias[col];
                if constexpr (EPI & E_LEAKY) v = v >= 0.f ? v : 0.2f * v;
                if constexpr (EPI & E_BN)
                    v = (v - bnm[col]) * (bng[col] * rsqrtf(bnv[col] + 1e-5f)) + bnbt[col];
                if constexpr (EPI & E_GELU) v = 0.5f * v * (1.f + erff(v * 0.70710678118654752f));
                if constexpr (EPI & E_RES) v += resid[(size_t)row * N + col];
                if constexpr (EPI & E_OUTF) outF[(size_t)row * N + col] = v;
                if constexpr (EPI & E_OUTB) outB[(size_t)row * N + col] = f2bf(v);
            }
        }
    }
}

// ---------------- flash attention: block = (qchunk 64, head, batch), 4 waves x 16 q-rows ----------------
__global__ __launch_bounds__(256) void attn_k(const u16* __restrict__ qkv, u16* __restrict__ outp)
{
    __shared__ u16 Ks[64 * 64];
    __shared__ u16 Vt[64 * 64];
    __shared__ u16 Ps[4][16 * 64];
    const int tid = threadIdx.x;
    const int lane = tid & 63, w = tid >> 6;
    const int l15 = lane & 15, hi4 = lane >> 4;
    const int qc = blockIdx.x, h = blockIdx.y, b = blockIdx.z;
    const int qrow = qc * 64 + w * 16 + l15;
    const size_t tq = ((size_t)b * 512 + qrow) * 1536 + h * 64;
    bf16x8 qf0 = *(const bf16x8*)&qkv[tq + hi4 * 8];
    bf16x8 qf1 = *(const bf16x8*)&qkv[tq + 32 + hi4 * 8];
    const float slope = exp2f(-(float)(h + 1));
    const f32x4 fz = {0.f, 0.f, 0.f, 0.f};
    float m_run = -3.0e38f, l_run = 0.f;
    f32x4 oacc[4] = {fz, fz, fz, fz};

    for (int j = 0; j < 8; ++j) {
        __syncthreads();
        #pragma unroll
        for (int p = 0; p < 2; ++p) {
            int idx = p * 256 + tid;
            int r = idx >> 3, c = idx & 7;
            size_t tk = ((size_t)b * 512 + j * 64 + r) * 1536 + h * 64;
            uint4 kvec = *(const uint4*)&qkv[tk + 512 + c * 8];
            *(uint4*)&Ks[r * 64 + c * 8] = kvec;
            uint4 vvec = *(const uint4*)&qkv[tk + 1024 + c * 8];
            u32 vv_[4] = {vvec.x, vvec.y, vvec.z, vvec.w};
            #pragma unroll
            for (int q2 = 0; q2 < 4; ++q2) {
                Vt[(c * 8 + q2 * 2) * 64 + r] = (u16)(vv_[q2] & 0xffffu);
                Vt[(c * 8 + q2 * 2 + 1) * 64 + r] = (u16)(vv_[q2] >> 16);
            }
        }
        __syncthreads();
        // scores: S^T tiles via mfma(K, Q): lane holds q=l15, k = j*64 + g*16 + hi4*4 + r
        float s[16];
        #pragma unroll
        for (int g = 0; g < 4; ++g) {
            f32x4 st = fz;
            bf16x8 kf0 = *(const bf16x8*)&Ks[(g * 16 + l15) * 64 + hi4 * 8];
            st = __builtin_amdgcn_mfma_f32_16x16x32_bf16(kf0, qf0, st, 0, 0, 0);
            bf16x8 kf1 = *(const bf16x8*)&Ks[(g * 16 + l15) * 64 + 32 + hi4 * 8];
            st = __builtin_amdgcn_mfma_f32_16x16x32_bf16(kf1, qf1, st, 0, 0, 0);
            #pragma unroll
            for (int r = 0; r < 4; ++r) {
                int kabs = j * 64 + g * 16 + hi4 * 4 + r;
                s[g * 4 + r] = st[r] * 0.125f - slope * fabsf((float)(qrow - kabs));
            }
        }
        // online softmax (row = q = l15, replicated over hi4 groups)
        float pm = s[0];
        #pragma unroll
        for (int i = 1; i < 16; ++i) pm = fmaxf(pm, s[i]);
        pm = fmaxf(pm, __shfl_xor(pm, 16));
        pm = fmaxf(pm, __shfl_xor(pm, 32));
        float m_new = fmaxf(m_run, pm);
        float alpha = expf(m_run - m_new);
        float p[16], ps = 0.f;
        #pragma unroll
        for (int i = 0; i < 16; ++i) { p[i] = expf(s[i] - m_new); ps += p[i]; }
        ps += __shfl_xor(ps, 16);
        ps += __shfl_xor(ps, 32);
        l_run = l_run * alpha + ps;
        m_run = m_new;
        #pragma unroll
        for (int n = 0; n < 4; ++n) oacc[n] *= alpha;
        // P -> LDS (wave-private region), row q, contiguous k
        #pragma unroll
        for (int g = 0; g < 4; ++g)
            #pragma unroll
            for (int rp = 0; rp < 2; ++rp) {
                u32 pk = (u32)f2bf(p[g * 4 + rp * 2]) | ((u32)f2bf(p[g * 4 + rp * 2 + 1]) << 16);
                *(u32*)&Ps[w][l15 * 64 + g * 16 + hi4 * 4 + rp * 2] = pk;
            }
        // O^T += V^T @ P^T : mfma(A=Vt rows (d), B=P rows (q))
        #pragma unroll
        for (int n = 0; n < 4; ++n) {
            #pragma unroll
            for (int kk = 0; kk < 2; ++kk) {
                bf16x8 vf = *(const bf16x8*)&Vt[(n * 16 + l15) * 64 + kk * 32 + hi4 * 8];
                bf16x8 pf = *(const bf16x8*)&Ps[w][l15 * 64 + kk * 32 + hi4 * 8];
                oacc[n] = __builtin_amdgcn_mfma_f32_16x16x32_bf16(vf, pf, oacc[n], 0, 0, 0);
            }
        }
    }
    const float inv = 1.f / l_run;
    const size_t to = ((size_t)b * 512 + qrow) * 512 + h * 64;
    #pragma unroll
    for (int n = 0; n < 4; ++n) {
        u32 lo = (u32)f2bf(oacc[n][0] * inv) | ((u32)f2bf(oacc[n][1] * inv) << 16);
        u32 hi = (u32)f2bf(oacc[n][2] * inv) | ((u32)f2bf(oacc[n][3] * inv) << 16);
        *(uint2*)&outp[to + n * 16 + hi4 * 4] = make_uint2(lo, hi);
    }
}

// ---------------- LayerNorm: wave per row, writes f32 residual + bf16 ----------------
__global__ __launch_bounds__(256) void ln_k(const float* __restrict__ in,
    const float* __restrict__ g, const float* __restrict__ bt,
    float* __restrict__ outF, u16* __restrict__ outB)
{
    const int lane = threadIdx.x & 63, w = threadIdx.x >> 6;
    const size_t row = (size_t)blockIdx.x * 4 + w;
    const float* rp = in + row * 512;
    const int c0 = lane * 8;
    float4 a = *(const float4*)&rp[c0];
    float4 bv = *(const float4*)&rp[c0 + 4];
    float v[8] = {a.x, a.y, a.z, a.w, bv.x, bv.y, bv.z, bv.w};
    float s = 0.f, q = 0.f;
    #pragma unroll
    for (int i = 0; i < 8; ++i) { s += v[i]; q += v[i] * v[i]; }
    #pragma unroll
    for (int d = 1; d < 64; d <<= 1) { s += __shfl_xor(s, d); q += __shfl_xor(q, d); }
    float mean = s * (1.f / 512.f);
    float var = q * (1.f / 512.f) - mean * mean;
    float rstd = rsqrtf(var + 1e-5f);
    float y[8];
    #pragma unroll
    for (int i = 0; i < 8; ++i) y[i] = (v[i] - mean) * rstd * g[c0 + i] + bt[c0 + i];
    *(float4*)&outF[row * 512 + c0] = make_float4(y[0], y[1], y[2], y[3]);
    *(float4*)&outF[row * 512 + c0 + 4] = make_float4(y[4], y[5], y[6], y[7]);
    u32 pk[4];
    #pragma unroll
    for (int i = 0; i < 4; ++i)
        pk[i] = (u32)f2bf(y[i * 2]) | ((u32)f2bf(y[i * 2 + 1]) << 16);
    *(uint4*)&outB[row * 512 + c0] = make_uint4(pk[0], pk[1], pk[2], pk[3]);
}

extern "C" void kernel_launch(void* const* d_in, const int* in_sizes, int n_in,
                              void* d_out, int out_size, void* d_ws, size_t ws_size,
                              hipStream_t stream)
{
    (void)in_sizes; (void)n_in; (void)out_size; (void)ws_size;
    const float* inputs   = (const float*)d_in[0];
    const float* deconv_w = (const float*)d_in[1];
    const float* deconv_b = (const float*)d_in[2];
    const float* bn_gamma = (const float*)d_in[3];
    const float* bn_beta  = (const float*)d_in[4];
    const float* bn_mean  = (const float*)d_in[5];
    const float* bn_var   = (const float*)d_in[6];
    const float* conv_w   = (const float*)d_in[7];
    const float* conv_b   = (const float*)d_in[8];
    const float* emb_w    = (const float*)d_in[9];
    const float* emb_b    = (const float*)d_in[10];
    const float* qkv_w    = (const float*)d_in[11];
    const float* qkv_b    = (const float*)d_in[12];
    const float* outp_w   = (const float*)d_in[13];
    const float* outp_b   = (const float*)d_in[14];
    const float* ln1_g    = (const float*)d_in[15];
    const float* ln1_b    = (const float*)d_in[16];
    const float* ff1_w    = (const float*)d_in[17];
    const float* ff1_b    = (const float*)d_in[18];
    const float* ff2_w    = (const float*)d_in[19];
    const float* ff2_b    = (const float*)d_in[20];
    const float* ln2_g    = (const float*)d_in[21];
    const float* ln2_b    = (const float*)d_in[22];
    const float* smooth_w = (const float*)d_in[23];
    const float* smooth_b = (const float*)d_in[24];
    float* out = (float*)d_out;

    char* ws = (char*)d_ws;
    size_t off = 0;
    auto alloc = [&](size_t bytes) -> char* {
        char* p = ws + off;
        off += (bytes + 255) & ~(size_t)255;
        return p;
    };
    u16*   zrow    = (u16*)alloc(1024);
    u16*   Wd      = (u16*)alloc((size_t)512 * 2560 * 2);
    u16*   Wc      = (u16*)alloc((size_t)2 * 512 * 2560 * 2);
    u16*   Wsm     = (u16*)alloc((size_t)128 * 2560 * 2);
    u16*   emb_bw  = (u16*)alloc((size_t)512 * 512 * 2);
    u16*   qkv_bw  = (u16*)alloc((size_t)6 * 1536 * 512 * 2);
    u16*   outp_bw = (u16*)alloc((size_t)6 * 512 * 512 * 2);
    u16*   ff1_bw  = (u16*)alloc((size_t)6 * 2048 * 512 * 2);
    u16*   ff2_bw  = (u16*)alloc((size_t)6 * 512 * 2048 * 2);
    float* x_f     = (float*)alloc((size_t)8192 * 512 * 4);
    u16*   x_bf    = (u16*)alloc((size_t)8192 * 512 * 2);
    float* tmp_f   = (float*)alloc((size_t)8192 * 512 * 4);
    char*  scratch = alloc((size_t)8192 * 2048 * 2);   // 32 MB aliased region
    u16*   in_bf   = (u16*)(scratch);                  // 1 MB
    u16*   e0      = (u16*)(scratch + (1 << 20));      // 2 MB
    u16*   e1      = (u16*)(scratch + (3 << 20));      // 2 MB
    u16*   e2      = (u16*)(scratch + (5 << 20));      // 4 MB
    u16*   qkv_bf  = (u16*)(scratch);                  // 24 MB
    u16*   attn_bf = (u16*)(scratch + (24 << 20));     // 8 MB
    u16*   h_bf    = (u16*)(scratch);                  // 32 MB

    hipMemsetAsync(zrow, 0, 1024, stream);
    // ---- weight prep (bf16) ----
    cvt_bf_k<<<dim3(512), dim3(256), 0, stream>>>(inputs, in_bf, 131072);
    tdeconv_k<<<dim3(512), dim3(256), 0, stream>>>(deconv_w, Wd);
    tconv_k<<<dim3(512, 2), dim3(256), 0, stream>>>(conv_w, Wc);
    tsmooth_k<<<dim3(128), dim3(256), 0, stream>>>(smooth_w, Wsm);
    cvt_bf_k<<<dim3(256), dim3(256), 0, stream>>>(emb_w, emb_bw, 65536);
    cvt_bf_k<<<dim3(4608), dim3(256), 0, stream>>>(qkv_w, qkv_bw, 1179648);
    cvt_bf_k<<<dim3(1536), dim3(256), 0, stream>>>(outp_w, outp_bw, 393216);
    cvt_bf_k<<<dim3(6144), dim3(256), 0, stream>>>(ff1_w, ff1_bw, 1572864);
    cvt_bf_k<<<dim3(6144), dim3(256), 0, stream>>>(ff2_w, ff2_bw, 1572864);

    // ---- expander ----
    gemm_k<M_DECONV, E_BIAS | E_LEAKY | E_BN | E_OUTB, 64, 64, 2, 2><<<dim3(8, 32), 256, 0, stream>>>(
        in_bf, Wd, deconv_b, bn_gamma, bn_beta, bn_mean, bn_var,
        nullptr, nullptr, e0, zrow, 512, 2560);
    gemm_k<M_CONV1, E_BIAS | E_LEAKY | E_BN | E_OUTB, 64, 64, 2, 2><<<dim3(8, 32), 256, 0, stream>>>(
        e0, Wc, conv_b, bn_gamma + 512, bn_beta + 512, bn_mean + 512, bn_var + 512,
        nullptr, nullptr, e1, zrow, 512, 2560);
    gemm_k<M_CONV2, E_BIAS | E_LEAKY | E_BN | E_OUTB, 64, 64, 2, 2><<<dim3(8, 64), 256, 0, stream>>>(
        e1, Wc + (size_t)512 * 2560, conv_b + 512, bn_gamma + 1024, bn_beta + 1024,
        bn_mean + 1024, bn_var + 1024, nullptr, nullptr, e2, zrow, 512, 2560);
    gemm_k<M_EMBED, E_BIAS | E_OUTF | E_OUTB, 128, 64, 4, 1><<<dim3(8, 64), 256, 0, stream>>>(
        e2, emb_bw, emb_b, nullptr, nullptr, nullptr, nullptr,
        nullptr, x_f, x_bf, zrow, 512, 512);

    // ---- transformer ----
    for (int l = 0; l < 6; ++l) {
        gemm_k<M_IDENT, E_BIAS | E_OUTB, 128, 128, 2, 2><<<dim3(12, 64), 256, 0, stream>>>(
            x_bf, qkv_bw + (size_t)l * 1536 * 512, qkv_b + l * 1536,
            nullptr, nullptr, nullptr, nullptr, nullptr, nullptr, qkv_bf, zrow, 1536, 512);
        attn_k<<<dim3(8, 8, 16), 256, 0, stream>>>(qkv_bf, attn_bf);
        gemm_k<M_IDENT, E_BIAS | E_RES | E_OUTF, 128, 64, 4, 1><<<dim3(8, 64), 256, 0, stream>>>(
            attn_bf, outp_bw + (size_t)l * 512 * 512, outp_b + l * 512,
            nullptr, nullptr, nullptr, nullptr, x_f, tmp_f, nullptr, zrow, 512, 512);
        ln_k<<<dim3(2048), 256, 0, stream>>>(tmp_f, ln1_g + l * 512, ln1_b + l * 512, x_f, x_bf);
        gemm_k<M_IDENT, E_BIAS | E_GELU | E_OUTB, 128, 128, 2, 2><<<dim3(16, 64), 256, 0, stream>>>(
            x_bf, ff1_bw + (size_t)l * 2048 * 512, ff1_b + l * 2048,
            nullptr, nullptr, nullptr, nullptr, nullptr, nullptr, h_bf, zrow, 2048, 512);
        gemm_k<M_IDENT, E_BIAS | E_RES | E_OUTF, 128, 64, 4, 1><<<dim3(8, 64), 256, 0, stream>>>(
            h_bf, ff2_bw + (size_t)l * 512 * 2048, ff2_b + l * 512,
            nullptr, nullptr, nullptr, nullptr, x_f, tmp_f, nullptr, zrow, 512, 2048);
        ln_k<<<dim3(2048), 256, 0, stream>>>(tmp_f, ln2_g + l * 512, ln2_b + l * 512, x_f, x_bf);
    }

    // ---- smooth conv -> output ----
    gemm_k<M_SMOOTH, E_BIAS | E_OUTF, 64, 64, 2, 2><<<dim3(2, 128), 256, 0, stream>>>(
        x_bf, Wsm, smooth_b, nullptr, nullptr, nullptr, nullptr,
        nullptr, out, nullptr, zrow, 128, 2560);
}

// Round 3
// 1278.305 us; speedup vs baseline: 1.4491x; 1.0758x over previous
//
#include <hip/hip_runtime.h>
#include <hip/hip_bf16.h>
#include <math.h>

typedef unsigned int u32;
typedef unsigned short u16;
typedef __bf16 bf16t;
typedef bf16t bf16x8 __attribute__((ext_vector_type(8)));
typedef float f32x4 __attribute__((ext_vector_type(4)));

__device__ __forceinline__ u16 f2bf(float f) {
    u32 u = __builtin_bit_cast(u32, f);
    u32 r = (u + 0x7fffu + ((u >> 16) & 1u)) >> 16;
    return (u16)r;
}

__device__ __forceinline__ void gl_lds16(const u16* g, u16* l) {
    __builtin_amdgcn_global_load_lds(
        (const __attribute__((address_space(1))) void*)g,
        (__attribute__((address_space(3))) void*)l, 16, 0, 0);
}

__device__ __forceinline__ void wait_vm0_barrier() {
    asm volatile("s_waitcnt vmcnt(0)" ::: "memory");
    __builtin_amdgcn_s_barrier();
}

// ---------------- weight layout transforms (-> bf16, (o, k*512+i)) ----------------
__global__ void tdeconv_k(const float* __restrict__ src, u16* __restrict__ dst) {
    int o = blockIdx.x;
    for (int i = threadIdx.x; i < 512; i += blockDim.x) {
        const float* s = src + ((size_t)i * 512 + o) * 5;   // deconv_w (in, out, K)
        #pragma unroll
        for (int k = 0; k < 5; ++k)
            dst[(size_t)o * 2560 + k * 512 + i] = f2bf(s[k]);
    }
}
__global__ void tconv_k(const float* __restrict__ src, u16* __restrict__ dst) {
    int o = blockIdx.x, st = blockIdx.y;
    const float* bsrc = src + (size_t)st * 512 * 512 * 5;   // conv_w (2, out, in, K)
    u16* bdst = dst + (size_t)st * 512 * 2560;
    for (int i = threadIdx.x; i < 512; i += blockDim.x) {
        const float* s = bsrc + ((size_t)o * 512 + i) * 5;
        #pragma unroll
        for (int k = 0; k < 5; ++k)
            bdst[(size_t)o * 2560 + k * 512 + i] = f2bf(s[k]);
    }
}
__global__ void tsmooth_k(const float* __restrict__ src, u16* __restrict__ dst) {
    int o = blockIdx.x;                                      // smooth_w (OUT, in, K)
    for (int i = threadIdx.x; i < 512; i += blockDim.x) {
        const float* s = src + ((size_t)o * 512 + i) * 5;
        #pragma unroll
        for (int k = 0; k < 5; ++k)
            dst[(size_t)o * 2560 + k * 512 + i] = f2bf(s[k]);
    }
}
__global__ void cvt_bf_k(const float* __restrict__ in, u16* __restrict__ out, int n4) {
    int i = blockIdx.x * blockDim.x + threadIdx.x;
    if (i < n4) {
        float4 v = ((const float4*)in)[i];
        u32 lo = (u32)f2bf(v.x) | ((u32)f2bf(v.y) << 16);
        u32 hi = (u32)f2bf(v.z) | ((u32)f2bf(v.w) << 16);
        ((uint2*)out)[i] = make_uint2(lo, hi);
    }
}

// ---------------- universal GEMM: C[M,N] = gatherA[M,K](bf16) @ W[N,K](bf16) ----------------
// LDS layout: tile rows of 32 bf16 (64B). Swizzle: 16B-chunk c stored at c ^ ((row>>1)&3).
enum { M_IDENT = 0, M_DECONV, M_CONV1, M_CONV2, M_EMBED, M_SMOOTH };
enum { E_BIAS = 1, E_LEAKY = 2, E_BN = 4, E_GELU = 8, E_RES = 16, E_OUTF = 32, E_OUTB = 64 };

template<int MODE, int EPI, int BM, int BN, int WM, int WN>
__global__ __launch_bounds__(256) void gemm_k(
    const u16* __restrict__ A, const u16* __restrict__ W,
    const float* __restrict__ bias,
    const float* __restrict__ bng, const float* __restrict__ bnbt,
    const float* __restrict__ bnm, const float* __restrict__ bnv,
    const float* __restrict__ resid,
    float* __restrict__ outF, u16* __restrict__ outB,
    const u16* __restrict__ zrow, int N, int K)
{
    constexpr int FM = BM / WM / 16, FN = BN / WN / 16;
    constexpr int APW = BM / 64, BPW = BN / 64;   // 1KB staging chunks per wave
    __shared__ u16 As[2][BM * 32];
    __shared__ u16 Bs[2][BN * 32];
    const int tid = threadIdx.x;
    const int lane = tid & 63, w = tid >> 6;
    const int l15 = lane & 15, hi4 = lane >> 4;
    const int bn = blockIdx.x, bm = blockIdx.y;
    const int wr = w / WN, wc = w % WN;
    const int rowb = wr * (BM / WM), colb = wc * (BN / WN);
    const int lr = lane >> 2;
    const int lcs = ((lane & 3) ^ ((lane >> 3) & 3)) * 8;   // pre-swizzled source chunk
    f32x4 acc[FM][FN] = {};
    const int nt = K >> 5;

    auto stage = [&](int t, int buf) {
        const int k0 = t * 32;
        const int tap = k0 >> 9;
        const int koff = (k0 & 511) + lcs;
        u16* Ab = As[buf];
        u16* Bb = Bs[buf];
        #pragma unroll
        for (int p = 0; p < APW; ++p) {
            const int j = w * APW + p;
            const int r = j * 16 + lr;
            const int grow = bm * BM + r;
            const u16* src;
            if constexpr (MODE == M_IDENT) {
                src = A + (size_t)grow * K + k0 + lcs;
            } else if constexpr (MODE == M_DECONV) {
                int b = grow >> 7, tt = grow & 127;
                int num = tt + 2 - tap;
                bool ok = (num >= 0) && ((num & 1) == 0) && ((num >> 1) < 64);
                src = ok ? (A + ((size_t)(b * 64 + (num >> 1))) * 512 + koff) : (zrow + koff);
            } else if constexpr (MODE == M_CONV1) {
                int b = grow >> 7, tt = grow & 127;
                int s = tt + tap - 2; s = s < 0 ? 0 : (s > 127 ? 127 : s);
                src = A + ((size_t)(b * 128 + s)) * 512 + koff;
            } else if constexpr (MODE == M_CONV2) {
                int b = grow >> 8, tt = grow & 255;
                int s = tt + tap - 2; s = s < 0 ? 0 : (s > 255 ? 255 : s);
                src = A + ((size_t)(b * 128 + (s >> 1))) * 512 + koff;
            } else if constexpr (MODE == M_EMBED) {
                int b = grow >> 9, tt = grow & 511;
                src = A + ((size_t)(b * 256 + (tt >> 1))) * 512 + koff;
            } else { // M_SMOOTH
                int b = grow >> 9, tt = grow & 511;
                int s = tt + tap - 2;
                bool ok = (s >= 0) && (s < 512);
                src = ok ? (A + ((size_t)(b * 512 + s)) * 512 + koff) : (zrow + koff);
            }
            gl_lds16(src, &Ab[j * 512]);
        }
        #pragma unroll
        for (int p = 0; p < BPW; ++p) {
            const int j = w * BPW + p;
            const int r = j * 16 + lr;
            gl_lds16(W + (size_t)(bn * BN + r) * K + k0 + lcs, &Bb[j * 512]);
        }
    };

    auto compute = [&](int buf) {
        const u16* Ab = As[buf];
        const u16* Bb = Bs[buf];
        bf16x8 af[FM], bfr[FN];
        #pragma unroll
        for (int mi = 0; mi < FM; ++mi) {
            const int R = rowb + mi * 16 + l15;
            af[mi] = *(const bf16x8*)&Ab[R * 32 + ((hi4 ^ ((R >> 1) & 3))) * 8];
        }
        #pragma unroll
        for (int ni = 0; ni < FN; ++ni) {
            const int R = colb + ni * 16 + l15;
            bfr[ni] = *(const bf16x8*)&Bb[R * 32 + ((hi4 ^ ((R >> 1) & 3))) * 8];
        }
        #pragma unroll
        for (int mi = 0; mi < FM; ++mi)
            #pragma unroll
            for (int ni = 0; ni < FN; ++ni)
                acc[mi][ni] = __builtin_amdgcn_mfma_f32_16x16x32_bf16(af[mi], bfr[ni], acc[mi][ni], 0, 0, 0);
    };

    stage(0, 0);
    wait_vm0_barrier();
    int cur = 0;
    for (int t = 0; t < nt - 1; ++t) {
        stage(t + 1, cur ^ 1);
        compute(cur);
        wait_vm0_barrier();
        cur ^= 1;
    }
    compute(cur);

    // ---- epilogue ----
    #pragma unroll
    for (int mi = 0; mi < FM; ++mi) {
        #pragma unroll
        for (int ni = 0; ni < FN; ++ni) {
            const int col = bn * BN + colb + ni * 16 + l15;
            #pragma unroll
            for (int r = 0; r < 4; ++r) {
                const int row = bm * BM + rowb + mi * 16 + hi4 * 4 + r;
                float v = acc[mi][ni][r];
                if constexpr (EPI & E_BIAS) v += bias[col];
                if constexpr (EPI & E_LEAKY) v = v >= 0.f ? v : 0.2f * v;
                if constexpr (EPI & E_BN)
                    v = (v - bnm[col]) * (bng[col] * rsqrtf(bnv[col] + 1e-5f)) + bnbt[col];
                if constexpr (EPI & E_GELU) v = 0.5f * v * (1.f + erff(v * 0.70710678118654752f));
                if constexpr (EPI & E_RES) v += resid[(size_t)row * N + col];
                if constexpr (EPI & E_OUTF) outF[(size_t)row * N + col] = v;
                if constexpr (EPI & E_OUTB) outB[(size_t)row * N + col] = f2bf(v);
            }
        }
    }
}

// ---------------- per-layer V transpose: qkv[t][h*64+d] (V part) -> vt[(b*8+h)*64+d][t] ----------------
__global__ __launch_bounds__(256) void vt_k(const u16* __restrict__ qkv, u16* __restrict__ vt)
{
    __shared__ u16 Ls[64 * 64];
    const int tid = threadIdx.x;
    const int blk = blockIdx.x;            // b*8+h
    const int b = blk >> 3, h = blk & 7;
    const int rd_d = tid >> 2, rd_c = tid & 3;
    for (int i = 0; i < 4; ++i) {
        const int tt = blockIdx.y * 4 + i;
        __syncthreads();
        #pragma unroll
        for (int p = 0; p < 2; ++p) {
            int idx = p * 256 + tid;
            int r = idx >> 3, c = idx & 7;
            *(uint4*)&Ls[r * 64 + c * 8] =
                *(const uint4*)&qkv[((size_t)(b * 512 + tt * 64 + r)) * 1536 + h * 64 + 1024 + c * 8];
        }
        __syncthreads();
        u16 tmp[16];
        #pragma unroll
        for (int s = 0; s < 16; ++s)
            tmp[s] = Ls[(rd_c * 16 + s) * 64 + rd_d];
        *(uint4*)&vt[((size_t)(blk * 64 + rd_d)) * 512 + tt * 64 + rd_c * 16] = *(uint4*)&tmp[0];
        *(uint4*)&vt[((size_t)(blk * 64 + rd_d)) * 512 + tt * 64 + rd_c * 16 + 8] = *(uint4*)&tmp[8];
    }
}

// ---------------- flash attention: block = (qchunk 64, head, batch), 4 waves x 16 q-rows ----------------
// K tile Ks[k=64][d=64], Vt tile Vs[d=64][k=64]: rows 128B, 16B-chunk c stored at c ^ (row&7).
// Ps[w][q=16][k=64]: rows 128B, 8-elem group o stored at o ^ ((q&7)<<3).
__global__ __launch_bounds__(256) void attn_k(const u16* __restrict__ qkv,
                                              const u16* __restrict__ vt,
                                              u16* __restrict__ outp)
{
    __shared__ u16 Ks[2][64 * 64];
    __shared__ u16 Vs[2][64 * 64];
    __shared__ u16 Ps[4][16 * 64];
    const int tid = threadIdx.x;
    const int lane = tid & 63, w = tid >> 6;
    const int l15 = lane & 15, hi4 = lane >> 4;
    const int qc = blockIdx.x, h = blockIdx.y, b = blockIdx.z;
    const int qrow = qc * 64 + w * 16 + l15;
    const size_t tq = ((size_t)b * 512 + qrow) * 1536 + h * 64;
    bf16x8 qf0 = *(const bf16x8*)&qkv[tq + hi4 * 8];
    bf16x8 qf1 = *(const bf16x8*)&qkv[tq + 32 + hi4 * 8];
    const float slope = exp2f(-(float)(h + 1));
    const f32x4 fz = {0.f, 0.f, 0.f, 0.f};
    float m_run = -3.0e38f, l_run = 0.f;
    f32x4 oacc[4] = {fz, fz, fz, fz};
    // staging source indices (pre-swizzled)
    const int sr = lane >> 3;                       // row within 8-row group
    const int sc = ((lane & 7) ^ sr) * 8;           // swizzled source chunk
    const int pswz = (l15 & 7) << 3;

    auto stage = [&](int j, int buf) {
        #pragma unroll
        for (int p = 0; p < 2; ++p) {
            const int q8 = w * 2 + p;
            const int r = q8 * 8 + sr;
            gl_lds16(qkv + ((size_t)(b * 512 + j * 64 + r)) * 1536 + h * 64 + 512 + sc,
                     &Ks[buf][q8 * 512]);
            gl_lds16(vt + ((size_t)((b * 8 + h) * 64 + r)) * 512 + j * 64 + sc,
                     &Vs[buf][q8 * 512]);
        }
    };

    stage(0, 0);
    wait_vm0_barrier();
    int cur = 0;
    for (int j = 0; j < 8; ++j) {
        if (j < 7) stage(j + 1, cur ^ 1);
        const u16* Kb = Ks[cur];
        const u16* Vb = Vs[cur];
        // scores via mfma(K, Q): lane holds q=l15, k = j*64 + g*16 + hi4*4 + r
        float s[16];
        #pragma unroll
        for (int g = 0; g < 4; ++g) {
            f32x4 st = fz;
            const int row = g * 16 + l15;
            bf16x8 kf0 = *(const bf16x8*)&Kb[row * 64 + (hi4 ^ (row & 7)) * 8];
            st = __builtin_amdgcn_mfma_f32_16x16x32_bf16(kf0, qf0, st, 0, 0, 0);
            bf16x8 kf1 = *(const bf16x8*)&Kb[row * 64 + ((hi4 + 4) ^ (row & 7)) * 8];
            st = __builtin_amdgcn_mfma_f32_16x16x32_bf16(kf1, qf1, st, 0, 0, 0);
            #pragma unroll
            for (int r = 0; r < 4; ++r) {
                int kabs = j * 64 + g * 16 + hi4 * 4 + r;
                s[g * 4 + r] = st[r] * 0.125f - slope * fabsf((float)(qrow - kabs));
            }
        }
        // online softmax (row = q = l15, replicated over hi4 groups)
        float pm = s[0];
        #pragma unroll
        for (int i = 1; i < 16; ++i) pm = fmaxf(pm, s[i]);
        pm = fmaxf(pm, __shfl_xor(pm, 16));
        pm = fmaxf(pm, __shfl_xor(pm, 32));
        float m_new = fmaxf(m_run, pm);
        float alpha = __expf(m_run - m_new);
        float p[16], ps = 0.f;
        #pragma unroll
        for (int i = 0; i < 16; ++i) { p[i] = __expf(s[i] - m_new); ps += p[i]; }
        ps += __shfl_xor(ps, 16);
        ps += __shfl_xor(ps, 32);
        l_run = l_run * alpha + ps;
        m_run = m_new;
        #pragma unroll
        for (int n = 0; n < 4; ++n) oacc[n] *= alpha;
        // P -> LDS (wave-private, swizzled)
        #pragma unroll
        for (int g = 0; g < 4; ++g)
            #pragma unroll
            for (int rp = 0; rp < 2; ++rp) {
                u32 pk = (u32)f2bf(p[g * 4 + rp * 2]) | ((u32)f2bf(p[g * 4 + rp * 2 + 1]) << 16);
                const int o = g * 16 + hi4 * 4 + rp * 2;
                *(u32*)&Ps[w][l15 * 64 + (o ^ pswz)] = pk;
            }
        // O^T += V^T @ P^T
        #pragma unroll
        for (int n = 0; n < 4; ++n) {
            const int d = n * 16 + l15;
            #pragma unroll
            for (int kk = 0; kk < 2; ++kk) {
                bf16x8 vf = *(const bf16x8*)&Vb[d * 64 + ((kk * 4 + hi4) ^ (d & 7)) * 8];
                bf16x8 pf = *(const bf16x8*)&Ps[w][l15 * 64 + ((kk * 32 + hi4 * 8) ^ pswz)];
                oacc[n] = __builtin_amdgcn_mfma_f32_16x16x32_bf16(vf, pf, oacc[n], 0, 0, 0);
            }
        }
        wait_vm0_barrier();
        cur ^= 1;
    }
    const float inv = 1.f / l_run;
    const size_t to = ((size_t)b * 512 + qrow) * 512 + h * 64;
    #pragma unroll
    for (int n = 0; n < 4; ++n) {
        u32 lo = (u32)f2bf(oacc[n][0] * inv) | ((u32)f2bf(oacc[n][1] * inv) << 16);
        u32 hi = (u32)f2bf(oacc[n][2] * inv) | ((u32)f2bf(oacc[n][3] * inv) << 16);
        *(uint2*)&outp[to + n * 16 + hi4 * 4] = make_uint2(lo, hi);
    }
}

// ---------------- LayerNorm: wave per row, writes f32 residual + bf16 ----------------
__global__ __launch_bounds__(256) void ln_k(const float* __restrict__ in,
    const float* __restrict__ g, const float* __restrict__ bt,
    float* __restrict__ outF, u16* __restrict__ outB)
{
    const int lane = threadIdx.x & 63, w = threadIdx.x >> 6;
    const size_t row = (size_t)blockIdx.x * 4 + w;
    const float* rp = in + row * 512;
    const int c0 = lane * 8;
    float4 a = *(const float4*)&rp[c0];
    float4 bv = *(const float4*)&rp[c0 + 4];
    float v[8] = {a.x, a.y, a.z, a.w, bv.x, bv.y, bv.z, bv.w};
    float s = 0.f, q = 0.f;
    #pragma unroll
    for (int i = 0; i < 8; ++i) { s += v[i]; q += v[i] * v[i]; }
    #pragma unroll
    for (int d = 1; d < 64; d <<= 1) { s += __shfl_xor(s, d); q += __shfl_xor(q, d); }
    float mean = s * (1.f / 512.f);
    float var = q * (1.f / 512.f) - mean * mean;
    float rstd = rsqrtf(var + 1e-5f);
    float y[8];
    #pragma unroll
    for (int i = 0; i < 8; ++i) y[i] = (v[i] - mean) * rstd * g[c0 + i] + bt[c0 + i];
    *(float4*)&outF[row * 512 + c0] = make_float4(y[0], y[1], y[2], y[3]);
    *(float4*)&outF[row * 512 + c0 + 4] = make_float4(y[4], y[5], y[6], y[7]);
    u32 pk[4];
    #pragma unroll
    for (int i = 0; i < 4; ++i)
        pk[i] = (u32)f2bf(y[i * 2]) | ((u32)f2bf(y[i * 2 + 1]) << 16);
    *(uint4*)&outB[row * 512 + c0] = make_uint4(pk[0], pk[1], pk[2], pk[3]);
}

extern "C" void kernel_launch(void* const* d_in, const int* in_sizes, int n_in,
                              void* d_out, int out_size, void* d_ws, size_t ws_size,
                              hipStream_t stream)
{
    (void)in_sizes; (void)n_in; (void)out_size; (void)ws_size;
    const float* inputs   = (const float*)d_in[0];
    const float* deconv_w = (const float*)d_in[1];
    const float* deconv_b = (const float*)d_in[2];
    const float* bn_gamma = (const float*)d_in[3];
    const float* bn_beta  = (const float*)d_in[4];
    const float* bn_mean  = (const float*)d_in[5];
    const float* bn_var   = (const float*)d_in[6];
    const float* conv_w   = (const float*)d_in[7];
    const float* conv_b   = (const float*)d_in[8];
    const float* emb_w    = (const float*)d_in[9];
    const float* emb_b    = (const float*)d_in[10];
    const float* qkv_w    = (const float*)d_in[11];
    const float* qkv_b    = (const float*)d_in[12];
    const float* outp_w   = (const float*)d_in[13];
    const float* outp_b   = (const float*)d_in[14];
    const float* ln1_g    = (const float*)d_in[15];
    const float* ln1_b    = (const float*)d_in[16];
    const float* ff1_w    = (const float*)d_in[17];
    const float* ff1_b    = (const float*)d_in[18];
    const float* ff2_w    = (const float*)d_in[19];
    const float* ff2_b    = (const float*)d_in[20];
    const float* ln2_g    = (const float*)d_in[21];
    const float* ln2_b    = (const float*)d_in[22];
    const float* smooth_w = (const float*)d_in[23];
    const float* smooth_b = (const float*)d_in[24];
    float* out = (float*)d_out;

    char* ws = (char*)d_ws;
    size_t off = 0;
    auto alloc = [&](size_t bytes) -> char* {
        char* p = ws + off;
        off += (bytes + 255) & ~(size_t)255;
        return p;
    };
    u16*   zrow    = (u16*)alloc(1024);
    u16*   Wd      = (u16*)alloc((size_t)512 * 2560 * 2);
    u16*   Wc      = (u16*)alloc((size_t)2 * 512 * 2560 * 2);
    u16*   Wsm     = (u16*)alloc((size_t)128 * 2560 * 2);
    u16*   emb_bw  = (u16*)alloc((size_t)512 * 512 * 2);
    u16*   qkv_bw  = (u16*)alloc((size_t)6 * 1536 * 512 * 2);
    u16*   outp_bw = (u16*)alloc((size_t)6 * 512 * 512 * 2);
    u16*   ff1_bw  = (u16*)alloc((size_t)6 * 2048 * 512 * 2);
    u16*   ff2_bw  = (u16*)alloc((size_t)6 * 512 * 2048 * 2);
    float* x_f     = (float*)alloc((size_t)8192 * 512 * 4);
    u16*   x_bf    = (u16*)alloc((size_t)8192 * 512 * 2);
    float* tmp_f   = (float*)alloc((size_t)8192 * 512 * 4);
    u16*   vtb     = (u16*)alloc((size_t)8192 * 512 * 2);
    char*  scratch = alloc((size_t)8192 * 2048 * 2);   // 32 MB aliased region
    u16*   in_bf   = (u16*)(scratch);                  // 1 MB
    u16*   e0      = (u16*)(scratch + (1 << 20));      // 2 MB
    u16*   e1      = (u16*)(scratch + (3 << 20));      // 2 MB
    u16*   e2      = (u16*)(scratch + (5 << 20));      // 4 MB
    u16*   qkv_bf  = (u16*)(scratch);                  // 24 MB
    u16*   attn_bf = (u16*)(scratch + (24 << 20));     // 8 MB
    u16*   h_bf    = (u16*)(scratch);                  // 32 MB

    hipMemsetAsync(zrow, 0, 1024, stream);
    // ---- weight prep (bf16) ----
    cvt_bf_k<<<dim3(512), dim3(256), 0, stream>>>(inputs, in_bf, 131072);
    tdeconv_k<<<dim3(512), dim3(256), 0, stream>>>(deconv_w, Wd);
    tconv_k<<<dim3(512, 2), dim3(256), 0, stream>>>(conv_w, Wc);
    tsmooth_k<<<dim3(128), dim3(256), 0, stream>>>(smooth_w, Wsm);
    cvt_bf_k<<<dim3(256), dim3(256), 0, stream>>>(emb_w, emb_bw, 65536);
    cvt_bf_k<<<dim3(4608), dim3(256), 0, stream>>>(qkv_w, qkv_bw, 1179648);
    cvt_bf_k<<<dim3(1536), dim3(256), 0, stream>>>(outp_w, outp_bw, 393216);
    cvt_bf_k<<<dim3(6144), dim3(256), 0, stream>>>(ff1_w, ff1_bw, 1572864);
    cvt_bf_k<<<dim3(6144), dim3(256), 0, stream>>>(ff2_w, ff2_bw, 1572864);

    // ---- expander ----
    gemm_k<M_DECONV, E_BIAS | E_LEAKY | E_BN | E_OUTB, 64, 64, 2, 2><<<dim3(8, 32), 256, 0, stream>>>(
        in_bf, Wd, deconv_b, bn_gamma, bn_beta, bn_mean, bn_var,
        nullptr, nullptr, e0, zrow, 512, 2560);
    gemm_k<M_CONV1, E_BIAS | E_LEAKY | E_BN | E_OUTB, 64, 64, 2, 2><<<dim3(8, 32), 256, 0, stream>>>(
        e0, Wc, conv_b, bn_gamma + 512, bn_beta + 512, bn_mean + 512, bn_var + 512,
        nullptr, nullptr, e1, zrow, 512, 2560);
    gemm_k<M_CONV2, E_BIAS | E_LEAKY | E_BN | E_OUTB, 64, 64, 2, 2><<<dim3(8, 64), 256, 0, stream>>>(
        e1, Wc + (size_t)512 * 2560, conv_b + 512, bn_gamma + 1024, bn_beta + 1024,
        bn_mean + 1024, bn_var + 1024, nullptr, nullptr, e2, zrow, 512, 2560);
    gemm_k<M_EMBED, E_BIAS | E_OUTF | E_OUTB, 128, 64, 4, 1><<<dim3(8, 64), 256, 0, stream>>>(
        e2, emb_bw, emb_b, nullptr, nullptr, nullptr, nullptr,
        nullptr, x_f, x_bf, zrow, 512, 512);

    // ---- transformer ----
    for (int l = 0; l < 6; ++l) {
        gemm_k<M_IDENT, E_BIAS | E_OUTB, 128, 128, 2, 2><<<dim3(12, 64), 256, 0, stream>>>(
            x_bf, qkv_bw + (size_t)l * 1536 * 512, qkv_b + l * 1536,
            nullptr, nullptr, nullptr, nullptr, nullptr, nullptr, qkv_bf, zrow, 1536, 512);
        vt_k<<<dim3(128, 2), 256, 0, stream>>>(qkv_bf, vtb);
        attn_k<<<dim3(8, 8, 16), 256, 0, stream>>>(qkv_bf, vtb, attn_bf);
        gemm_k<M_IDENT, E_BIAS | E_RES | E_OUTF, 128, 64, 4, 1><<<dim3(8, 64), 256, 0, stream>>>(
            attn_bf, outp_bw + (size_t)l * 512 * 512, outp_b + l * 512,
            nullptr, nullptr, nullptr, nullptr, x_f, tmp_f, nullptr, zrow, 512, 512);
        ln_k<<<dim3(2048), 256, 0, stream>>>(tmp_f, ln1_g + l * 512, ln1_b + l * 512, x_f, x_bf);
        gemm_k<M_IDENT, E_BIAS | E_GELU | E_OUTB, 128, 128, 2, 2><<<dim3(16, 64), 256, 0, stream>>>(
            x_bf, ff1_bw + (size_t)l * 2048 * 512, ff1_b + l * 2048,
            nullptr, nullptr, nullptr, nullptr, nullptr, nullptr, h_bf, zrow, 2048, 512);
        gemm_k<M_IDENT, E_BIAS | E_RES | E_OUTF, 128, 64, 4, 1><<<dim3(8, 64), 256, 0, stream>>>(
            h_bf, ff2_bw + (size_t)l * 512 * 2048, ff2_b + l * 512,
            nullptr, nullptr, nullptr, nullptr, x_f, tmp_f, nullptr, zrow, 512, 2048);
        ln_k<<<dim3(2048), 256, 0, stream>>>(tmp_f, ln2_g + l * 512, ln2_b + l * 512, x_f, x_bf);
    }

    // ---- smooth conv -> output ----
    gemm_k<M_SMOOTH, E_BIAS | E_OUTF, 64, 64, 2, 2><<<dim3(2, 128), 256, 0, stream>>>(
        x_bf, Wsm, smooth_b, nullptr, nullptr, nullptr, nullptr,
        nullptr, out, nullptr, zrow, 128, 2560);
}

// Round 4
// 1204.231 us; speedup vs baseline: 1.5383x; 1.0615x over previous
//
#include <hip/hip_runtime.h>
#include <hip/hip_bf16.h>
#include <math.h>

typedef unsigned int u32;
typedef unsigned short u16;
typedef __bf16 bf16t;
typedef bf16t bf16x8 __attribute__((ext_vector_type(8)));
typedef float f32x4 __attribute__((ext_vector_type(4)));

__device__ __forceinline__ u16 f2bf(float f) {
    u32 u = __builtin_bit_cast(u32, f);
    u32 r = (u + 0x7fffu + ((u >> 16) & 1u)) >> 16;
    return (u16)r;
}

__device__ __forceinline__ void gl_lds16(const u16* g, u16* l) {
    __builtin_amdgcn_global_load_lds(
        (const __attribute__((address_space(1))) void*)g,
        (__attribute__((address_space(3))) void*)l, 16, 0, 0);
}

__device__ __forceinline__ void wait_vm0_barrier() {
    asm volatile("s_waitcnt vmcnt(0)" ::: "memory");
    __builtin_amdgcn_s_barrier();
}

template<int N> __device__ __forceinline__ void s_wait_vmcnt() {
    if constexpr (N == 0) asm volatile("s_waitcnt vmcnt(0)" ::: "memory");
    else if constexpr (N == 2) asm volatile("s_waitcnt vmcnt(2)" ::: "memory");
    else if constexpr (N == 3) asm volatile("s_waitcnt vmcnt(3)" ::: "memory");
    else if constexpr (N == 4) asm volatile("s_waitcnt vmcnt(4)" ::: "memory");
    else static_assert(N == 0 || N == 2 || N == 3 || N == 4, "unsupported vmcnt");
}

// ---------------- weight layout transforms (-> bf16, (o, k*512+i)) ----------------
__global__ void tdeconv_k(const float* __restrict__ src, u16* __restrict__ dst) {
    int o = blockIdx.x;
    for (int i = threadIdx.x; i < 512; i += blockDim.x) {
        const float* s = src + ((size_t)i * 512 + o) * 5;   // deconv_w (in, out, K)
        #pragma unroll
        for (int k = 0; k < 5; ++k)
            dst[(size_t)o * 2560 + k * 512 + i] = f2bf(s[k]);
    }
}
__global__ void tconv_k(const float* __restrict__ src, u16* __restrict__ dst) {
    int o = blockIdx.x, st = blockIdx.y;
    const float* bsrc = src + (size_t)st * 512 * 512 * 5;   // conv_w (2, out, in, K)
    u16* bdst = dst + (size_t)st * 512 * 2560;
    for (int i = threadIdx.x; i < 512; i += blockDim.x) {
        const float* s = bsrc + ((size_t)o * 512 + i) * 5;
        #pragma unroll
        for (int k = 0; k < 5; ++k)
            bdst[(size_t)o * 2560 + k * 512 + i] = f2bf(s[k]);
    }
}
__global__ void tsmooth_k(const float* __restrict__ src, u16* __restrict__ dst) {
    int o = blockIdx.x;                                      // smooth_w (OUT, in, K)
    for (int i = threadIdx.x; i < 512; i += blockDim.x) {
        const float* s = src + ((size_t)o * 512 + i) * 5;
        #pragma unroll
        for (int k = 0; k < 5; ++k)
            dst[(size_t)o * 2560 + k * 512 + i] = f2bf(s[k]);
    }
}
__global__ void cvt_bf_k(const float* __restrict__ in, u16* __restrict__ out, int n4) {
    int i = blockIdx.x * blockDim.x + threadIdx.x;
    if (i < n4) {
        float4 v = ((const float4*)in)[i];
        u32 lo = (u32)f2bf(v.x) | ((u32)f2bf(v.y) << 16);
        u32 hi = (u32)f2bf(v.z) | ((u32)f2bf(v.w) << 16);
        ((uint2*)out)[i] = make_uint2(lo, hi);
    }
}

// ---------------- universal GEMM: C[M,N] = gatherA[M,K](bf16) @ W[N,K](bf16) ----------------
// 1-D grid (nwg % 8 == 0), XCD-chunked swizzle. 3-buffer LDS ring, counted vmcnt.
// LDS rows of 32 bf16 (64B); 16B-chunk c stored at c ^ ((row>>1)&3) (via pre-swizzled source).
enum { M_IDENT = 0, M_DECONV, M_CONV1, M_CONV2, M_EMBED, M_SMOOTH };
enum { E_BIAS = 1, E_LEAKY = 2, E_BN = 4, E_GELU = 8, E_RES = 16, E_OUTF = 32, E_OUTB = 64 };

template<int MODE, int EPI, int BM, int BN, int WM, int WN>
__global__ __launch_bounds__(256) void gemm_k(
    const u16* __restrict__ A, const u16* __restrict__ W,
    const float* __restrict__ bias,
    const float* __restrict__ bng, const float* __restrict__ bnbt,
    const float* __restrict__ bnm, const float* __restrict__ bnv,
    const float* __restrict__ resid,
    float* __restrict__ outF, u16* __restrict__ outB,
    const u16* __restrict__ zrow, int gn, int N, int K)
{
    constexpr int FM = BM / WM / 16, FN = BN / WN / 16;
    constexpr int APW = BM / 64, BPW = BN / 64;   // 1KB staging chunks per wave
    constexpr int LPW = APW + BPW;                // vm ops per wave per stage
    __shared__ u16 As[3][BM * 32];
    __shared__ u16 Bs[3][BN * 32];
    const int tid = threadIdx.x;
    const int lane = tid & 63, w = tid >> 6;
    const int l15 = lane & 15, hi4 = lane >> 4;
    // XCD-chunked block swizzle (requires gridDim.x % 8 == 0)
    const int nwg = gridDim.x;
    int wid = blockIdx.x;
    wid = (wid & 7) * (nwg >> 3) + (wid >> 3);
    const int bn = wid % gn, bm = wid / gn;
    const int wr = w / WN, wc = w % WN;
    const int rowb = wr * (BM / WM), colb = wc * (BN / WN);
    const int lr = lane >> 2;
    const int lcs = ((lane & 3) ^ ((lane >> 3) & 3)) * 8;   // pre-swizzled source chunk
    f32x4 acc[FM][FN] = {};
    const int nt = K >> 5;

    auto stage = [&](int t, int buf) {
        const int k0 = t * 32;
        const int tap = k0 >> 9;
        const int koff = (k0 & 511) + lcs;
        u16* Ab = As[buf];
        u16* Bb = Bs[buf];
        #pragma unroll
        for (int p = 0; p < APW; ++p) {
            const int j = w * APW + p;
            const int r = j * 16 + lr;
            const int grow = bm * BM + r;
            const u16* src;
            if constexpr (MODE == M_IDENT) {
                src = A + (size_t)grow * K + k0 + lcs;
            } else if constexpr (MODE == M_DECONV) {
                int b = grow >> 7, tt = grow & 127;
                int num = tt + 2 - tap;
                bool ok = (num >= 0) && ((num & 1) == 0) && ((num >> 1) < 64);
                src = ok ? (A + ((size_t)(b * 64 + (num >> 1))) * 512 + koff) : (zrow + koff);
            } else if constexpr (MODE == M_CONV1) {
                int b = grow >> 7, tt = grow & 127;
                int s = tt + tap - 2; s = s < 0 ? 0 : (s > 127 ? 127 : s);
                src = A + ((size_t)(b * 128 + s)) * 512 + koff;
            } else if constexpr (MODE == M_CONV2) {
                int b = grow >> 8, tt = grow & 255;
                int s = tt + tap - 2; s = s < 0 ? 0 : (s > 255 ? 255 : s);
                src = A + ((size_t)(b * 128 + (s >> 1))) * 512 + koff;
            } else if constexpr (MODE == M_EMBED) {
                int b = grow >> 9, tt = grow & 511;
                src = A + ((size_t)(b * 256 + (tt >> 1))) * 512 + koff;
            } else { // M_SMOOTH
                int b = grow >> 9, tt = grow & 511;
                int s = tt + tap - 2;
                bool ok = (s >= 0) && (s < 512);
                src = ok ? (A + ((size_t)(b * 512 + s)) * 512 + koff) : (zrow + koff);
            }
            gl_lds16(src, &Ab[j * 512]);
        }
        #pragma unroll
        for (int p = 0; p < BPW; ++p) {
            const int j = w * BPW + p;
            const int r = j * 16 + lr;
            gl_lds16(W + (size_t)(bn * BN + r) * K + k0 + lcs, &Bb[j * 512]);
        }
    };

    auto compute = [&](int buf) {
        const u16* Ab = As[buf];
        const u16* Bb = Bs[buf];
        bf16x8 af[FM], bfr[FN];
        #pragma unroll
        for (int mi = 0; mi < FM; ++mi) {
            const int R = rowb + mi * 16 + l15;
            af[mi] = *(const bf16x8*)&Ab[R * 32 + ((hi4 ^ ((R >> 1) & 3))) * 8];
        }
        #pragma unroll
        for (int ni = 0; ni < FN; ++ni) {
            const int R = colb + ni * 16 + l15;
            bfr[ni] = *(const bf16x8*)&Bb[R * 32 + ((hi4 ^ ((R >> 1) & 3))) * 8];
        }
        #pragma unroll
        for (int mi = 0; mi < FM; ++mi)
            #pragma unroll
            for (int ni = 0; ni < FN; ++ni)
                acc[mi][ni] = __builtin_amdgcn_mfma_f32_16x16x32_bf16(af[mi], bfr[ni], acc[mi][ni], 0, 0, 0);
    };

    stage(0, 0);
    stage(1, 1);
    int cur = 0;
    for (int t = 0; t < nt; ++t) {
        if (t == nt - 1) s_wait_vmcnt<0>(); else s_wait_vmcnt<LPW>();
        __builtin_amdgcn_s_barrier();
        compute(cur);
        if (t + 2 < nt) {
            int nb = cur + 2; if (nb >= 3) nb -= 3;
            stage(t + 2, nb);
        }
        ++cur; if (cur == 3) cur = 0;
    }

    // ---- epilogue ----
    #pragma unroll
    for (int mi = 0; mi < FM; ++mi) {
        #pragma unroll
        for (int ni = 0; ni < FN; ++ni) {
            const int col = bn * BN + colb + ni * 16 + l15;
            #pragma unroll
            for (int r = 0; r < 4; ++r) {
                const int row = bm * BM + rowb + mi * 16 + hi4 * 4 + r;
                float v = acc[mi][ni][r];
                if constexpr (EPI & E_BIAS) v += bias[col];
                if constexpr (EPI & E_LEAKY) v = v >= 0.f ? v : 0.2f * v;
                if constexpr (EPI & E_BN)
                    v = (v - bnm[col]) * (bng[col] * rsqrtf(bnv[col] + 1e-5f)) + bnbt[col];
                if constexpr (EPI & E_GELU) v = 0.5f * v * (1.f + erff(v * 0.70710678118654752f));
                if constexpr (EPI & E_RES) v += resid[(size_t)row * N + col];
                if constexpr (EPI & E_OUTF) outF[(size_t)row * N + col] = v;
                if constexpr (EPI & E_OUTB) outB[(size_t)row * N + col] = f2bf(v);
            }
        }
    }
}

// ---------------- per-layer V transpose: qkv[t][h*64+d] (V part) -> vt[(b*8+h)*64+d][t] ----------------
__global__ __launch_bounds__(256) void vt_k(const u16* __restrict__ qkv, u16* __restrict__ vt)
{
    __shared__ u16 Ls[64 * 64];
    const int tid = threadIdx.x;
    const int blk = blockIdx.x;            // b*8+h
    const int b = blk >> 3, h = blk & 7;
    const int rd_d = tid >> 2, rd_c = tid & 3;
    for (int i = 0; i < 4; ++i) {
        const int tt = blockIdx.y * 4 + i;
        __syncthreads();
        #pragma unroll
        for (int p = 0; p < 2; ++p) {
            int idx = p * 256 + tid;
            int r = idx >> 3, c = idx & 7;
            *(uint4*)&Ls[r * 64 + c * 8] =
                *(const uint4*)&qkv[((size_t)(b * 512 + tt * 64 + r)) * 1536 + h * 64 + 1024 + c * 8];
        }
        __syncthreads();
        u16 tmp[16];
        #pragma unroll
        for (int s = 0; s < 16; ++s)
            tmp[s] = Ls[(rd_c * 16 + s) * 64 + rd_d];
        *(uint4*)&vt[((size_t)(blk * 64 + rd_d)) * 512 + tt * 64 + rd_c * 16] = *(uint4*)&tmp[0];
        *(uint4*)&vt[((size_t)(blk * 64 + rd_d)) * 512 + tt * 64 + rd_c * 16 + 8] = *(uint4*)&tmp[8];
    }
}

// ---------------- flash attention: block = (qchunk 64, head, batch), 4 waves x 16 q-rows ----------------
// K tile Ks[k=64][d=64], Vt tile Vs[d=64][k=64]: rows 128B, 16B-chunk c stored at c ^ (row&7).
// Ps[w][q=16][k=64]: rows 128B, 8-elem group o stored at o ^ ((q&7)<<3).
__global__ __launch_bounds__(256) void attn_k(const u16* __restrict__ qkv,
                                              const u16* __restrict__ vt,
                                              u16* __restrict__ outp)
{
    __shared__ u16 Ks[2][64 * 64];
    __shared__ u16 Vs[2][64 * 64];
    __shared__ u16 Ps[4][16 * 64];
    const int tid = threadIdx.x;
    const int lane = tid & 63, w = tid >> 6;
    const int l15 = lane & 15, hi4 = lane >> 4;
    const int qc = blockIdx.x, h = blockIdx.y, b = blockIdx.z;
    const int qrow = qc * 64 + w * 16 + l15;
    const size_t tq = ((size_t)b * 512 + qrow) * 1536 + h * 64;
    bf16x8 qf0 = *(const bf16x8*)&qkv[tq + hi4 * 8];
    bf16x8 qf1 = *(const bf16x8*)&qkv[tq + 32 + hi4 * 8];
    const float slope = exp2f(-(float)(h + 1));
    const f32x4 fz = {0.f, 0.f, 0.f, 0.f};
    float m_run = -3.0e38f, l_run = 0.f;
    f32x4 oacc[4] = {fz, fz, fz, fz};
    const int sr = lane >> 3;                       // row within 8-row group
    const int sc = ((lane & 7) ^ sr) * 8;           // swizzled source chunk
    const int pswz = (l15 & 7) << 3;

    auto stage = [&](int j, int buf) {
        #pragma unroll
        for (int p = 0; p < 2; ++p) {
            const int q8 = w * 2 + p;
            const int r = q8 * 8 + sr;
            gl_lds16(qkv + ((size_t)(b * 512 + j * 64 + r)) * 1536 + h * 64 + 512 + sc,
                     &Ks[buf][q8 * 512]);
            gl_lds16(vt + ((size_t)((b * 8 + h) * 64 + r)) * 512 + j * 64 + sc,
                     &Vs[buf][q8 * 512]);
        }
    };

    stage(0, 0);
    wait_vm0_barrier();
    int cur = 0;
    for (int j = 0; j < 8; ++j) {
        if (j < 7) stage(j + 1, cur ^ 1);
        const u16* Kb = Ks[cur];
        const u16* Vb = Vs[cur];
        float s[16];
        #pragma unroll
        for (int g = 0; g < 4; ++g) {
            f32x4 st = fz;
            const int row = g * 16 + l15;
            bf16x8 kf0 = *(const bf16x8*)&Kb[row * 64 + (hi4 ^ (row & 7)) * 8];
            st = __builtin_amdgcn_mfma_f32_16x16x32_bf16(kf0, qf0, st, 0, 0, 0);
            bf16x8 kf1 = *(const bf16x8*)&Kb[row * 64 + ((hi4 + 4) ^ (row & 7)) * 8];
            st = __builtin_amdgcn_mfma_f32_16x16x32_bf16(kf1, qf1, st, 0, 0, 0);
            #pragma unroll
            for (int r = 0; r < 4; ++r) {
                int kabs = j * 64 + g * 16 + hi4 * 4 + r;
                s[g * 4 + r] = st[r] * 0.125f - slope * fabsf((float)(qrow - kabs));
            }
        }
        float pm = s[0];
        #pragma unroll
        for (int i = 1; i < 16; ++i) pm = fmaxf(pm, s[i]);
        pm = fmaxf(pm, __shfl_xor(pm, 16));
        pm = fmaxf(pm, __shfl_xor(pm, 32));
        float m_new = fmaxf(m_run, pm);
        float alpha = __expf(m_run - m_new);
        float p[16], ps = 0.f;
        #pragma unroll
        for (int i = 0; i < 16; ++i) { p[i] = __expf(s[i] - m_new); ps += p[i]; }
        ps += __shfl_xor(ps, 16);
        ps += __shfl_xor(ps, 32);
        l_run = l_run * alpha + ps;
        m_run = m_new;
        #pragma unroll
        for (int n = 0; n < 4; ++n) oacc[n] *= alpha;
        #pragma unroll
        for (int g = 0; g < 4; ++g)
            #pragma unroll
            for (int rp = 0; rp < 2; ++rp) {
                u32 pk = (u32)f2bf(p[g * 4 + rp * 2]) | ((u32)f2bf(p[g * 4 + rp * 2 + 1]) << 16);
                const int o = g * 16 + hi4 * 4 + rp * 2;
                *(u32*)&Ps[w][l15 * 64 + (o ^ pswz)] = pk;
            }
        #pragma unroll
        for (int n = 0; n < 4; ++n) {
            const int d = n * 16 + l15;
            #pragma unroll
            for (int kk = 0; kk < 2; ++kk) {
                bf16x8 vf = *(const bf16x8*)&Vb[d * 64 + ((kk * 4 + hi4) ^ (d & 7)) * 8];
                bf16x8 pf = *(const bf16x8*)&Ps[w][l15 * 64 + ((kk * 32 + hi4 * 8) ^ pswz)];
                oacc[n] = __builtin_amdgcn_mfma_f32_16x16x32_bf16(vf, pf, oacc[n], 0, 0, 0);
            }
        }
        wait_vm0_barrier();
        cur ^= 1;
    }
    const float inv = 1.f / l_run;
    const size_t to = ((size_t)b * 512 + qrow) * 512 + h * 64;
    #pragma unroll
    for (int n = 0; n < 4; ++n) {
        u32 lo = (u32)f2bf(oacc[n][0] * inv) | ((u32)f2bf(oacc[n][1] * inv) << 16);
        u32 hi = (u32)f2bf(oacc[n][2] * inv) | ((u32)f2bf(oacc[n][3] * inv) << 16);
        *(uint2*)&outp[to + n * 16 + hi4 * 4] = make_uint2(lo, hi);
    }
}

// ---------------- LayerNorm: wave per row, writes f32 residual + bf16 ----------------
__global__ __launch_bounds__(256) void ln_k(const float* __restrict__ in,
    const float* __restrict__ g, const float* __restrict__ bt,
    float* __restrict__ outF, u16* __restrict__ outB)
{
    const int lane = threadIdx.x & 63, w = threadIdx.x >> 6;
    const size_t row = (size_t)blockIdx.x * 4 + w;
    const float* rp = in + row * 512;
    const int c0 = lane * 8;
    float4 a = *(const float4*)&rp[c0];
    float4 bv = *(const float4*)&rp[c0 + 4];
    float v[8] = {a.x, a.y, a.z, a.w, bv.x, bv.y, bv.z, bv.w};
    float s = 0.f, q = 0.f;
    #pragma unroll
    for (int i = 0; i < 8; ++i) { s += v[i]; q += v[i] * v[i]; }
    #pragma unroll
    for (int d = 1; d < 64; d <<= 1) { s += __shfl_xor(s, d); q += __shfl_xor(q, d); }
    float mean = s * (1.f / 512.f);
    float var = q * (1.f / 512.f) - mean * mean;
    float rstd = rsqrtf(var + 1e-5f);
    float y[8];
    #pragma unroll
    for (int i = 0; i < 8; ++i) y[i] = (v[i] - mean) * rstd * g[c0 + i] + bt[c0 + i];
    *(float4*)&outF[row * 512 + c0] = make_float4(y[0], y[1], y[2], y[3]);
    *(float4*)&outF[row * 512 + c0 + 4] = make_float4(y[4], y[5], y[6], y[7]);
    u32 pk[4];
    #pragma unroll
    for (int i = 0; i < 4; ++i)
        pk[i] = (u32)f2bf(y[i * 2]) | ((u32)f2bf(y[i * 2 + 1]) << 16);
    *(uint4*)&outB[row * 512 + c0] = make_uint4(pk[0], pk[1], pk[2], pk[3]);
}

extern "C" void kernel_launch(void* const* d_in, const int* in_sizes, int n_in,
                              void* d_out, int out_size, void* d_ws, size_t ws_size,
                              hipStream_t stream)
{
    (void)in_sizes; (void)n_in; (void)out_size; (void)ws_size;
    const float* inputs   = (const float*)d_in[0];
    const float* deconv_w = (const float*)d_in[1];
    const float* deconv_b = (const float*)d_in[2];
    const float* bn_gamma = (const float*)d_in[3];
    const float* bn_beta  = (const float*)d_in[4];
    const float* bn_mean  = (const float*)d_in[5];
    const float* bn_var   = (const float*)d_in[6];
    const float* conv_w   = (const float*)d_in[7];
    const float* conv_b   = (const float*)d_in[8];
    const float* emb_w    = (const float*)d_in[9];
    const float* emb_b    = (const float*)d_in[10];
    const float* qkv_w    = (const float*)d_in[11];
    const float* qkv_b    = (const float*)d_in[12];
    const float* outp_w   = (const float*)d_in[13];
    const float* outp_b   = (const float*)d_in[14];
    const float* ln1_g    = (const float*)d_in[15];
    const float* ln1_b    = (const float*)d_in[16];
    const float* ff1_w    = (const float*)d_in[17];
    const float* ff1_b    = (const float*)d_in[18];
    const float* ff2_w    = (const float*)d_in[19];
    const float* ff2_b    = (const float*)d_in[20];
    const float* ln2_g    = (const float*)d_in[21];
    const float* ln2_b    = (const float*)d_in[22];
    const float* smooth_w = (const float*)d_in[23];
    const float* smooth_b = (const float*)d_in[24];
    float* out = (float*)d_out;

    char* ws = (char*)d_ws;
    size_t off = 0;
    auto alloc = [&](size_t bytes) -> char* {
        char* p = ws + off;
        off += (bytes + 255) & ~(size_t)255;
        return p;
    };
    u16*   zrow    = (u16*)alloc(1024);
    u16*   Wd      = (u16*)alloc((size_t)512 * 2560 * 2);
    u16*   Wc      = (u16*)alloc((size_t)2 * 512 * 2560 * 2);
    u16*   Wsm     = (u16*)alloc((size_t)128 * 2560 * 2);
    u16*   emb_bw  = (u16*)alloc((size_t)512 * 512 * 2);
    u16*   qkv_bw  = (u16*)alloc((size_t)6 * 1536 * 512 * 2);
    u16*   outp_bw = (u16*)alloc((size_t)6 * 512 * 512 * 2);
    u16*   ff1_bw  = (u16*)alloc((size_t)6 * 2048 * 512 * 2);
    u16*   ff2_bw  = (u16*)alloc((size_t)6 * 512 * 2048 * 2);
    float* x_f     = (float*)alloc((size_t)8192 * 512 * 4);
    u16*   x_bf    = (u16*)alloc((size_t)8192 * 512 * 2);
    float* tmp_f   = (float*)alloc((size_t)8192 * 512 * 4);
    u16*   vtb     = (u16*)alloc((size_t)8192 * 512 * 2);
    char*  scratch = alloc((size_t)8192 * 2048 * 2);   // 32 MB aliased region
    u16*   in_bf   = (u16*)(scratch);                  // 1 MB
    u16*   e0      = (u16*)(scratch + (1 << 20));      // 2 MB
    u16*   e1      = (u16*)(scratch + (3 << 20));      // 2 MB
    u16*   e2      = (u16*)(scratch + (5 << 20));      // 4 MB
    u16*   qkv_bf  = (u16*)(scratch);                  // 24 MB
    u16*   attn_bf = (u16*)(scratch + (24 << 20));     // 8 MB
    u16*   h_bf    = (u16*)(scratch);                  // 32 MB

    hipMemsetAsync(zrow, 0, 1024, stream);
    // ---- weight prep (bf16) ----
    cvt_bf_k<<<dim3(512), dim3(256), 0, stream>>>(inputs, in_bf, 131072);
    tdeconv_k<<<dim3(512), dim3(256), 0, stream>>>(deconv_w, Wd);
    tconv_k<<<dim3(512, 2), dim3(256), 0, stream>>>(conv_w, Wc);
    tsmooth_k<<<dim3(128), dim3(256), 0, stream>>>(smooth_w, Wsm);
    cvt_bf_k<<<dim3(256), dim3(256), 0, stream>>>(emb_w, emb_bw, 65536);
    cvt_bf_k<<<dim3(4608), dim3(256), 0, stream>>>(qkv_w, qkv_bw, 1179648);
    cvt_bf_k<<<dim3(1536), dim3(256), 0, stream>>>(outp_w, outp_bw, 393216);
    cvt_bf_k<<<dim3(6144), dim3(256), 0, stream>>>(ff1_w, ff1_bw, 1572864);
    cvt_bf_k<<<dim3(6144), dim3(256), 0, stream>>>(ff2_w, ff2_bw, 1572864);

    // ---- expander ----
    gemm_k<M_DECONV, E_BIAS | E_LEAKY | E_BN | E_OUTB, 64, 64, 2, 2><<<dim3(256), 256, 0, stream>>>(
        in_bf, Wd, deconv_b, bn_gamma, bn_beta, bn_mean, bn_var,
        nullptr, nullptr, e0, zrow, 8, 512, 2560);
    gemm_k<M_CONV1, E_BIAS | E_LEAKY | E_BN | E_OUTB, 64, 64, 2, 2><<<dim3(256), 256, 0, stream>>>(
        e0, Wc, conv_b, bn_gamma + 512, bn_beta + 512, bn_mean + 512, bn_var + 512,
        nullptr, nullptr, e1, zrow, 8, 512, 2560);
    gemm_k<M_CONV2, E_BIAS | E_LEAKY | E_BN | E_OUTB, 64, 64, 2, 2><<<dim3(512), 256, 0, stream>>>(
        e1, Wc + (size_t)512 * 2560, conv_b + 512, bn_gamma + 1024, bn_beta + 1024,
        bn_mean + 1024, bn_var + 1024, nullptr, nullptr, e2, zrow, 8, 512, 2560);
    gemm_k<M_EMBED, E_BIAS | E_OUTF | E_OUTB, 128, 64, 4, 1><<<dim3(512), 256, 0, stream>>>(
        e2, emb_bw, emb_b, nullptr, nullptr, nullptr, nullptr,
        nullptr, x_f, x_bf, zrow, 8, 512, 512);

    // ---- transformer ----
    for (int l = 0; l < 6; ++l) {
        gemm_k<M_IDENT, E_BIAS | E_OUTB, 128, 128, 2, 2><<<dim3(768), 256, 0, stream>>>(
            x_bf, qkv_bw + (size_t)l * 1536 * 512, qkv_b + l * 1536,
            nullptr, nullptr, nullptr, nullptr, nullptr, nullptr, qkv_bf, zrow, 12, 1536, 512);
        vt_k<<<dim3(128, 2), 256, 0, stream>>>(qkv_bf, vtb);
        attn_k<<<dim3(8, 8, 16), 256, 0, stream>>>(qkv_bf, vtb, attn_bf);
        gemm_k<M_IDENT, E_BIAS | E_RES | E_OUTF, 128, 64, 4, 1><<<dim3(512), 256, 0, stream>>>(
            attn_bf, outp_bw + (size_t)l * 512 * 512, outp_b + l * 512,
            nullptr, nullptr, nullptr, nullptr, x_f, tmp_f, nullptr, zrow, 8, 512, 512);
        ln_k<<<dim3(2048), 256, 0, stream>>>(tmp_f, ln1_g + l * 512, ln1_b + l * 512, x_f, x_bf);
        gemm_k<M_IDENT, E_BIAS | E_GELU | E_OUTB, 128, 128, 2, 2><<<dim3(1024), 256, 0, stream>>>(
            x_bf, ff1_bw + (size_t)l * 2048 * 512, ff1_b + l * 2048,
            nullptr, nullptr, nullptr, nullptr, nullptr, nullptr, h_bf, zrow, 16, 2048, 512);
        gemm_k<M_IDENT, E_BIAS | E_RES | E_OUTF, 128, 64, 4, 1><<<dim3(512), 256, 0, stream>>>(
            h_bf, ff2_bw + (size_t)l * 512 * 2048, ff2_b + l * 512,
            nullptr, nullptr, nullptr, nullptr, x_f, tmp_f, nullptr, zrow, 8, 512, 2048);
        ln_k<<<dim3(2048), 256, 0, stream>>>(tmp_f, ln2_g + l * 512, ln2_b + l * 512, x_f, x_bf);
    }

    // ---- smooth conv -> output ----
    gemm_k<M_SMOOTH, E_BIAS | E_OUTF, 64, 64, 2, 2><<<dim3(256), 256, 0, stream>>>(
        x_bf, Wsm, smooth_b, nullptr, nullptr, nullptr, nullptr,
        nullptr, out, nullptr, zrow, 2, 128, 2560);
}